// Round 12
// baseline (1014.145 us; speedup 1.0000x reference)
//
#include <hip/hip_runtime.h>
#include <hip/hip_cooperative_groups.h>

namespace cg = cooperative_groups;

#define NEG_SLOPE 0.2f

typedef __attribute__((ext_vector_type(8))) short short8;
typedef __attribute__((ext_vector_type(4))) float floatx4;
typedef unsigned short ushort_t;

static __device__ __forceinline__ float leaky(float x){ return x > 0.f ? x : NEG_SLOPE * x; }

static __device__ __forceinline__ unsigned short bf16_rne(float x){
  unsigned u = __float_as_uint(x);
  unsigned r = (u + 0x7fffu + ((u >> 16) & 1u)) >> 16;
  return (unsigned short)r;
}
static __device__ __forceinline__ float bf16_to_f(unsigned short h){
  return __uint_as_float(((unsigned)h) << 16);
}

#define GLOAD_LDS16(g, l) \
  __builtin_amdgcn_global_load_lds((const __attribute__((address_space(1))) unsigned*)(g), \
                                   (__attribute__((address_space(3))) unsigned*)(l), 16, 0, 0)

// ---------------- Cooperative build kernel ----------------
// One launch replaces: memset(deg), deg, scan_part, scan_top, scan_fin,
// scatter, sortrows, wprep, xprep. Phases separated by grid.sync();
// phase 0 runs the independent prep (zero/wprep/xprep) concurrently.
// All arithmetic bit-identical to the previous multi-kernel chain.

__global__ __launch_bounds__(256) void coop_build_kernel(
    const int* __restrict__ edges, const float* __restrict__ x,
    const float* __restrict__ W1, const float* __restrict__ W2, const float* __restrict__ W3,
    int* __restrict__ deg, int* __restrict__ partial, int* __restrict__ row_ptr,
    int* __restrict__ cursor, float* __restrict__ inv, int* __restrict__ col,
    ushort_t* __restrict__ xb, ushort_t* __restrict__ wt1, ushort_t* __restrict__ wt2,
    ushort_t* __restrict__ wt3, int N, int E, int nPart){
  cg::grid_group grid = cg::this_grid();
  __shared__ int sh4[4];
  const int tid  = threadIdx.x;
  const int gsz  = gridDim.x * 256;
  const int gtid = blockIdx.x * 256 + tid;

  // ---- phase 0: zero deg ; wprep (transpose W -> bf16 [N][K]) ; xprep ----
  for (int i = gtid; i < N; i += gsz) deg[i] = 0;
  for (int i = gtid; i < 131072; i += gsz){
    const float* W; ushort_t* tp; int K, Nw, idx;
    if (i < 32768)      { W = W1; tp = wt1; K = 128; Nw = 256; idx = i; }
    else if (i < 98304) { W = W2; tp = wt2; K = 256; Nw = 256; idx = i - 32768; }
    else                { W = W3; tp = wt3; K = 256; Nw = 128; idx = i - 98304; }
    int k = idx / Nw, n = idx - k * Nw;
    tp[(size_t)n * K + k] = bf16_rne(W[idx]);
  }
  int totx = (N * 128) / 8;
  for (int i = gtid; i < totx; i += gsz){
    int base = i * 8;
    float4 a = *(const float4*)(x + base);
    float4 b = *(const float4*)(x + base + 4);
    short8 o;
    o[0] = (short)bf16_rne(a.x); o[1] = (short)bf16_rne(a.y);
    o[2] = (short)bf16_rne(a.z); o[3] = (short)bf16_rne(a.w);
    o[4] = (short)bf16_rne(b.x); o[5] = (short)bf16_rne(b.y);
    o[6] = (short)bf16_rne(b.z); o[7] = (short)bf16_rne(b.w);
    *(short8*)(xb + base) = o;
  }
  grid.sync();

  // ---- phase 1: degree count ----
  for (int i = gtid; i < E; i += gsz) atomicAdd(&deg[edges[2*i + 1]], 1);
  grid.sync();

  // ---- phase 2: per-256-chunk partial sums ----
  for (int b = blockIdx.x; b < nPart; b += gridDim.x){
    int i = b * 256 + tid;
    int v = (i < N) ? deg[i] : 0;
    #pragma unroll
    for (int o = 32; o > 0; o >>= 1) v += __shfl_xor(v, o);
    if ((tid & 63) == 0) sh4[tid >> 6] = v;
    __syncthreads();
    if (tid == 0) partial[b] = sh4[0] + sh4[1] + sh4[2] + sh4[3];
    __syncthreads();
  }
  grid.sync();

  // ---- phase 3: exclusive scan of partials (block 0; nPart <= 256) ----
  if (blockIdx.x == 0){
    int lane = tid & 63, w = tid >> 6;
    int v = (tid < nPart) ? partial[tid] : 0;
    int sc = v;
    #pragma unroll
    for (int o = 1; o < 64; o <<= 1){
      int q = __shfl_up(sc, o);
      if (lane >= o) sc += q;
    }
    if (lane == 63) sh4[w] = sc;
    __syncthreads();
    int base = 0;
    for (int j = 0; j < w; j++) base += sh4[j];
    if (tid < nPart) partial[tid] = base + sc - v;
  }
  grid.sync();

  // ---- phase 4: block-local scan + offset -> row_ptr, cursor, inv ----
  for (int b = blockIdx.x; b < nPart; b += gridDim.x){
    int i = b * 256 + tid;
    int lane = tid & 63, w = tid >> 6;
    int v = (i < N) ? deg[i] : 0;
    int sc = v;
    #pragma unroll
    for (int o = 1; o < 64; o <<= 1){
      int q = __shfl_up(sc, o);
      if (lane >= o) sc += q;
    }
    if (lane == 63) sh4[w] = sc;
    __syncthreads();
    int base = partial[b];
    for (int j = 0; j < w; j++) base += sh4[j];
    int excl = base + sc - v;
    if (i < N){
      row_ptr[i] = excl;
      cursor[i]  = excl;
      inv[i] = (v > 0) ? 1.0f / (float)v : 0.0f;
      if (i == N - 1) row_ptr[N] = excl + v;
    }
    __syncthreads();
  }
  grid.sync();

  // ---- phase 5: scatter ----
  for (int i = gtid; i < E; i += gsz){
    int s = edges[2*i], d = edges[2*i + 1];
    int p = atomicAdd(&cursor[d], 1);
    col[p] = s;
  }
  grid.sync();

  // ---- phase 6: sort each row (deterministic summation order downstream) ----
  {
    int lane = tid & 63;
    int wslot = gtid >> 6;
    int nw = gsz >> 6;
    for (int r = wslot; r < N; r += nw){
      int s = row_ptr[r], e = row_ptr[r + 1];
      int len = e - s;
      if (len <= 1) continue;
      if (len <= 64){
        int v = (lane < len) ? col[s + lane] : 0x7fffffff;
        #pragma unroll
        for (int k = 2; k <= 64; k <<= 1){
          #pragma unroll
          for (int j = k >> 1; j > 0; j >>= 1){
            int o = __shfl_xor(v, j);
            bool dirUp = ((lane & k) == 0);
            bool takeMin = (((lane & j) == 0) == dirUp);
            v = takeMin ? min(v, o) : max(v, o);
          }
        }
        if (lane < len) col[s + lane] = v;
      } else if (lane == 0){
        for (int i = s + 1; i < e; ++i){
          int v = col[i];
          int j = i - 1;
          while (j >= s && col[j] > v){ col[j + 1] = col[j]; --j; }
          col[j + 1] = v;
        }
      }
    }
  }
}

// ---------------- MFMA GEMM (plain bf16 x bf16) ----------------
// A: [M][K] bf16, Bt: [N][K] bf16. f32 accum.
// 128x128 tile, 4 waves 2x2, BK=32, LDS double-buffered, one barrier/K-step.
// K-major granule-plane LDS (conflict-free). global_load_lds staging.
// MODE: 1 = bf16 out, leaky, bias masked by inv>0; 2 = bf16 out + bias.

template<int MODE>
__global__ __launch_bounds__(256) void gemm_mfma_kernel(
    const ushort_t* __restrict__ A, const ushort_t* __restrict__ Bt,
    const float* __restrict__ bias, const float* __restrict__ invv,
    ushort_t* __restrict__ Cp,
    int M, int K, int N){
  __shared__ ushort_t lds[2][8192];
  const int tid  = threadIdx.x;
  const int lane = tid & 63;
  const int wid  = tid >> 6;
  const int wrow = wid >> 1;
  const int wcol = wid & 1;
  const int br = blockIdx.x * 128;
  const int bc = blockIdx.y * 128;

  floatx4 acc[4][4];
  #pragma unroll
  for (int i = 0; i < 4; i++)
    #pragma unroll
    for (int j = 0; j < 4; j++) acc[i][j] = (floatx4){0.f, 0.f, 0.f, 0.f};

  auto STAGE = [&](int b, int k0){
    char* bufA = (char*)&lds[b][0];
    char* bufB = (char*)&lds[b][4096];
    #pragma unroll
    for (int q = 0; q < 2; q++){
      int c = q * 256 + tid;
      int g = c >> 7, r = c & 127;
      int grow = br + r;
      if (grow < M)
        GLOAD_LDS16(A + (size_t)grow * K + k0 + g * 8,
                    bufA + (q * 256 + wid * 64) * 16);
    }
    #pragma unroll
    for (int q = 0; q < 2; q++){
      int c = q * 256 + tid;
      int g = c >> 7, colc = c & 127;
      int gcol = bc + colc;
      GLOAD_LDS16(Bt + (size_t)gcol * K + k0 + g * 8,
                  bufB + (q * 256 + wid * 64) * 16);
    }
  };

  auto COMPUTE = [&](int b){
    const ushort_t* bufA = &lds[b][0];
    const ushort_t* bufB = &lds[b][4096];
    const int gsel = (lane >> 4) * 1024;
    short8 bh[4];
    #pragma unroll
    for (int nf = 0; nf < 4; nf++)
      bh[nf] = *(const short8*)(bufB + gsel + (wcol * 64 + nf * 16 + (lane & 15)) * 8);
    #pragma unroll
    for (int mf = 0; mf < 4; mf++){
      short8 ah = *(const short8*)(bufA + gsel + (wrow * 64 + mf * 16 + (lane & 15)) * 8);
      #pragma unroll
      for (int nf = 0; nf < 4; nf++)
        acc[mf][nf] = __builtin_amdgcn_mfma_f32_16x16x32_bf16(ah, bh[nf], acc[mf][nf], 0, 0, 0);
    }
  };

  const int nt = K >> 5;
  STAGE(0, 0);
  __syncthreads();
  for (int t = 0; t < nt; ++t){
    if (t + 1 < nt) STAGE((t + 1) & 1, (t + 1) << 5);
    COMPUTE(t & 1);
    __syncthreads();
  }

  const int r0 = br + wrow * 64;
  const int c0 = bc + wcol * 64;
  #pragma unroll
  for (int nf = 0; nf < 4; nf++){
    int col = c0 + nf * 16 + (lane & 15);
    float bv = bias[col];
    #pragma unroll
    for (int mf = 0; mf < 4; mf++){
      int rbase = r0 + mf * 16 + ((lane >> 4) << 2);
      #pragma unroll
      for (int j = 0; j < 4; j++){
        int r = rbase + j;
        if (r >= M) continue;
        if (MODE == 1){
          float m = (invv[r] > 0.f) ? 1.f : 0.f;
          Cp[(size_t)r * N + col] = bf16_rne(leaky(acc[mf][nf][j] + m * bv));
        } else {
          Cp[(size_t)r * N + col] = bf16_rne(acc[mf][nf][j] + bv);
        }
      }
    }
  }
}

// ---------------- SpMM kernels (CSR gather, bf16 src, f32 accum) ----------------

// xb (bf16 [n][128]) -> t (bf16 [n][128]); t = inv * sum
__global__ __launch_bounds__(256) void spmm128b_kernel(const ushort_t* __restrict__ xb,
    const int* __restrict__ row_ptr, const int* __restrict__ col,
    const float* __restrict__ inv, ushort_t* __restrict__ out, int n){
  int gw = (blockIdx.x * 256 + threadIdx.x) >> 5;
  int lane = threadIdx.x & 31;
  if (gw >= n) return;
  int s = row_ptr[gw], e = row_ptr[gw + 1];
  float ir = inv[gw];
  int off = lane * 4;
  float4 a0 = make_float4(0.f,0.f,0.f,0.f), a1 = make_float4(0.f,0.f,0.f,0.f);
  float4 a2 = make_float4(0.f,0.f,0.f,0.f), a3 = make_float4(0.f,0.f,0.f,0.f);
  int i = s;
  for (; i + 3 < e; i += 4){
    int c0 = col[i], c1 = col[i+1], c2 = col[i+2], c3 = col[i+3];
    ushort4 u0 = *(const ushort4*)(xb + (size_t)c0 * 128 + off);
    ushort4 u1 = *(const ushort4*)(xb + (size_t)c1 * 128 + off);
    ushort4 u2 = *(const ushort4*)(xb + (size_t)c2 * 128 + off);
    ushort4 u3 = *(const ushort4*)(xb + (size_t)c3 * 128 + off);
    a0.x += bf16_to_f(u0.x); a0.y += bf16_to_f(u0.y); a0.z += bf16_to_f(u0.z); a0.w += bf16_to_f(u0.w);
    a1.x += bf16_to_f(u1.x); a1.y += bf16_to_f(u1.y); a1.z += bf16_to_f(u1.z); a1.w += bf16_to_f(u1.w);
    a2.x += bf16_to_f(u2.x); a2.y += bf16_to_f(u2.y); a2.z += bf16_to_f(u2.z); a2.w += bf16_to_f(u2.w);
    a3.x += bf16_to_f(u3.x); a3.y += bf16_to_f(u3.y); a3.z += bf16_to_f(u3.z); a3.w += bf16_to_f(u3.w);
  }
  for (; i < e; ++i){
    int c0 = col[i];
    ushort4 u0 = *(const ushort4*)(xb + (size_t)c0 * 128 + off);
    a0.x += bf16_to_f(u0.x); a0.y += bf16_to_f(u0.y); a0.z += bf16_to_f(u0.z); a0.w += bf16_to_f(u0.w);
  }
  ushort4 ov;
  ov.x = bf16_rne(((a0.x + a1.x) + (a2.x + a3.x)) * ir);
  ov.y = bf16_rne(((a0.y + a1.y) + (a2.y + a3.y)) * ir);
  ov.z = bf16_rne(((a0.z + a1.z) + (a2.z + a3.z)) * ir);
  ov.w = bf16_rne(((a0.w + a1.w) + (a2.w + a3.w)) * ir);
  *(ushort4*)(out + (size_t)gw * 128 + off) = ov;
}

// s2 (bf16 [n][256]) -> h2 (bf16 [n][256]); h = leaky(inv * sum)
__global__ __launch_bounds__(256) void spmm256b_leaky_kernel(const ushort_t* __restrict__ sup,
    const int* __restrict__ row_ptr, const int* __restrict__ col,
    const float* __restrict__ inv, ushort_t* __restrict__ out, int n){
  int gw = (blockIdx.x * 256 + threadIdx.x) >> 6;
  int lane = threadIdx.x & 63;
  if (gw >= n) return;
  int s = row_ptr[gw], e = row_ptr[gw + 1];
  float ir = inv[gw];
  int off = lane * 4;
  float4 a0 = make_float4(0.f,0.f,0.f,0.f), a1 = make_float4(0.f,0.f,0.f,0.f);
  float4 a2 = make_float4(0.f,0.f,0.f,0.f), a3 = make_float4(0.f,0.f,0.f,0.f);
  int i = s;
  for (; i + 3 < e; i += 4){
    int c0 = col[i], c1 = col[i+1], c2 = col[i+2], c3 = col[i+3];
    ushort4 u0 = *(const ushort4*)(sup + (size_t)c0 * 256 + off);
    ushort4 u1 = *(const ushort4*)(sup + (size_t)c1 * 256 + off);
    ushort4 u2 = *(const ushort4*)(sup + (size_t)c2 * 256 + off);
    ushort4 u3 = *(const ushort4*)(sup + (size_t)c3 * 256 + off);
    a0.x += bf16_to_f(u0.x); a0.y += bf16_to_f(u0.y); a0.z += bf16_to_f(u0.z); a0.w += bf16_to_f(u0.w);
    a1.x += bf16_to_f(u1.x); a1.y += bf16_to_f(u1.y); a1.z += bf16_to_f(u1.z); a1.w += bf16_to_f(u1.w);
    a2.x += bf16_to_f(u2.x); a2.y += bf16_to_f(u2.y); a2.z += bf16_to_f(u2.z); a2.w += bf16_to_f(u2.w);
    a3.x += bf16_to_f(u3.x); a3.y += bf16_to_f(u3.y); a3.z += bf16_to_f(u3.z); a3.w += bf16_to_f(u3.w);
  }
  for (; i < e; ++i){
    int c0 = col[i];
    ushort4 u0 = *(const ushort4*)(sup + (size_t)c0 * 256 + off);
    a0.x += bf16_to_f(u0.x); a0.y += bf16_to_f(u0.y); a0.z += bf16_to_f(u0.z); a0.w += bf16_to_f(u0.w);
  }
  ushort4 ov;
  ov.x = bf16_rne(leaky(((a0.x + a1.x) + (a2.x + a3.x)) * ir));
  ov.y = bf16_rne(leaky(((a0.y + a1.y) + (a2.y + a3.y)) * ir));
  ov.z = bf16_rne(leaky(((a0.z + a1.z) + (a2.z + a3.z)) * ir));
  ov.w = bf16_rne(leaky(((a0.w + a1.w) + (a2.w + a3.w)) * ir));
  *(ushort4*)(out + (size_t)gw * 256 + off) = ov;
}

// s3 (bf16 [n][128]) -> out f32 [n][128]; inv-scale + L2 row-normalize
__global__ __launch_bounds__(256) void spmm_normb_kernel(const ushort_t* __restrict__ sup,
    const int* __restrict__ row_ptr, const int* __restrict__ col,
    const float* __restrict__ inv, float* __restrict__ out, int n){
  int gw = (blockIdx.x * 256 + threadIdx.x) >> 5;
  int lane = threadIdx.x & 31;
  if (gw >= n) return;
  int s = row_ptr[gw], e = row_ptr[gw + 1];
  float ir = inv[gw];
  int off = lane * 4;
  float4 a0 = make_float4(0.f,0.f,0.f,0.f), a1 = make_float4(0.f,0.f,0.f,0.f);
  float4 a2 = make_float4(0.f,0.f,0.f,0.f), a3 = make_float4(0.f,0.f,0.f,0.f);
  int i = s;
  for (; i + 3 < e; i += 4){
    int c0 = col[i], c1 = col[i+1], c2 = col[i+2], c3 = col[i+3];
    ushort4 u0 = *(const ushort4*)(sup + (size_t)c0 * 128 + off);
    ushort4 u1 = *(const ushort4*)(sup + (size_t)c1 * 128 + off);
    ushort4 u2 = *(const ushort4*)(sup + (size_t)c2 * 128 + off);
    ushort4 u3 = *(const ushort4*)(sup + (size_t)c3 * 128 + off);
    a0.x += bf16_to_f(u0.x); a0.y += bf16_to_f(u0.y); a0.z += bf16_to_f(u0.z); a0.w += bf16_to_f(u0.w);
    a1.x += bf16_to_f(u1.x); a1.y += bf16_to_f(u1.y); a1.z += bf16_to_f(u1.z); a1.w += bf16_to_f(u1.w);
    a2.x += bf16_to_f(u2.x); a2.y += bf16_to_f(u2.y); a2.z += bf16_to_f(u2.z); a2.w += bf16_to_f(u2.w);
    a3.x += bf16_to_f(u3.x); a3.y += bf16_to_f(u3.y); a3.z += bf16_to_f(u3.z); a3.w += bf16_to_f(u3.w);
  }
  for (; i < e; ++i){
    int c0 = col[i];
    ushort4 u0 = *(const ushort4*)(sup + (size_t)c0 * 128 + off);
    a0.x += bf16_to_f(u0.x); a0.y += bf16_to_f(u0.y); a0.z += bf16_to_f(u0.z); a0.w += bf16_to_f(u0.w);
  }
  float v0 = ((a0.x + a1.x) + (a2.x + a3.x)) * ir;
  float v1 = ((a0.y + a1.y) + (a2.y + a3.y)) * ir;
  float v2 = ((a0.z + a1.z) + (a2.z + a3.z)) * ir;
  float v3 = ((a0.w + a1.w) + (a2.w + a3.w)) * ir;
  float ss = v0*v0 + v1*v1 + v2*v2 + v3*v3;
  #pragma unroll
  for (int o = 16; o > 0; o >>= 1) ss += __shfl_xor(ss, o);
  float scale = 1.0f / fmaxf(sqrtf(ss), 1e-12f);
  float4 ov;
  ov.x = v0 * scale; ov.y = v1 * scale; ov.z = v2 * scale; ov.w = v3 * scale;
  *(float4*)(out + (size_t)gw * 128 + off) = ov;
}

// ---------------- launch ----------------

extern "C" void kernel_launch(void* const* d_in, const int* in_sizes, int n_in,
                              void* d_out, int out_size, void* d_ws, size_t ws_size,
                              hipStream_t stream){
  const int* edges = (const int*)d_in[7];
  const float* x  = (const float*)d_in[0];
  const float* W1 = (const float*)d_in[1];
  const float* b1 = (const float*)d_in[2];
  const float* W2 = (const float*)d_in[3];
  const float* b2 = (const float*)d_in[4];
  const float* W3 = (const float*)d_in[5];
  const float* b3 = (const float*)d_in[6];
  int N = in_sizes[0] / 128;
  int E = in_sizes[7] / 2;

  char* w = (char*)d_ws;
  size_t off = 0;
  auto alloc = [&](size_t bytes)->char*{
    char* p = w + off;
    off = (off + bytes + 255) & ~(size_t)255;
    return p;
  };
  int nPart = (N + 255) / 256;
  int*   deg     = (int*)  alloc((size_t)N * 4);
  float* inv     = (float*)alloc((size_t)N * 4);
  int*   row_ptr = (int*)  alloc(((size_t)N + 1) * 4);
  int*   cursor  = (int*)  alloc((size_t)N * 4);
  int*   colidx  = (int*)  alloc((size_t)E * 4);
  int*   partial = (int*)  alloc((size_t)nPart * 4);
  ushort_t* wt1 = (ushort_t*)alloc((size_t)128 * 256 * 2);
  ushort_t* wt2 = (ushort_t*)alloc((size_t)256 * 256 * 2);
  ushort_t* wt3 = (ushort_t*)alloc((size_t)256 * 128 * 2);
  char* slabA = alloc((size_t)N * 1024);   // 51.2 MB
  char* slabB = alloc((size_t)N * 1024);   // 51.2 MB

  ushort_t* xb     = (ushort_t*)slabA;                       // [N][128] bf16
  ushort_t* t_buf  = (ushort_t*)(slabA + (size_t)N * 256);   // [N][128] bf16
  ushort_t* s2_buf = (ushort_t*)(slabA + (size_t)N * 512);   // [N][256] bf16
  ushort_t* h1_buf = (ushort_t*)slabB;                       // [N][256] bf16
  ushort_t* h2_buf = (ushort_t*)(slabB + (size_t)N * 512);   // [N][256] bf16
  ushort_t* s3_buf = (ushort_t*)slabA;                       // [N][128] bf16 (aliases dead xb)

  // ---- single cooperative build launch (prep + CSR + sort) ----
  {
    void* args[] = {
      (void*)&edges, (void*)&x, (void*)&W1, (void*)&W2, (void*)&W3,
      (void*)&deg, (void*)&partial, (void*)&row_ptr, (void*)&cursor,
      (void*)&inv, (void*)&colidx, (void*)&xb, (void*)&wt1, (void*)&wt2,
      (void*)&wt3, (void*)&N, (void*)&E, (void*)&nPart
    };
    hipLaunchCooperativeKernel((void*)coop_build_kernel, dim3(1024), dim3(256),
                               args, 0, stream);
  }

  int gm = (N + 127) / 128;
  dim3 g12(gm, 2);
  dim3 g3 (gm, 1);
  int gS64 = (N * 64 + 255) / 256;
  int gS32 = (N * 32 + 255) / 256;

  // layer 1 (reordered): t = A_hat xb ; h1 = bf16(leaky(t@W1 + mask*b1))
  spmm128b_kernel<<<gS32, 256, 0, stream>>>(xb, row_ptr, colidx, inv, t_buf, N);
  gemm_mfma_kernel<1><<<g12, 256, 0, stream>>>(t_buf, wt1, b1, inv, h1_buf, N, 128, 256);
  // layer 2: s2 = bf16(h1@W2 + b2) ; h2 = bf16(leaky(A_hat s2))
  gemm_mfma_kernel<2><<<g12, 256, 0, stream>>>(h1_buf, wt2, b2, nullptr, s2_buf, N, 256, 256);
  spmm256b_leaky_kernel<<<gS64, 256, 0, stream>>>(s2_buf, row_ptr, colidx, inv, h2_buf, N);
  // layer 3: s3 = bf16(h2@W3 + b3) ; out = normalize(A_hat s3)
  gemm_mfma_kernel<2><<<g3, 256, 0, stream>>>(h2_buf, wt3, b3, nullptr, s3_buf, N, 256, 128);
  spmm_normb_kernel<<<gS32, 256, 0, stream>>>(s3_buf, row_ptr, colidx, inv, (float*)d_out, N);
}

// Round 13
// 336.125 us; speedup vs baseline: 3.0172x; 3.0172x over previous
//
#include <hip/hip_runtime.h>

#define NEG_SLOPE 0.2f

typedef __attribute__((ext_vector_type(8))) short short8;
typedef __attribute__((ext_vector_type(4))) float floatx4;
typedef unsigned short ushort_t;

static __device__ __forceinline__ float leaky(float x){ return x > 0.f ? x : NEG_SLOPE * x; }

static __device__ __forceinline__ unsigned short bf16_rne(float x){
  unsigned u = __float_as_uint(x);
  unsigned r = (u + 0x7fffu + ((u >> 16) & 1u)) >> 16;
  return (unsigned short)r;
}
static __device__ __forceinline__ float bf16_to_f(unsigned short h){
  return __uint_as_float(((unsigned)h) << 16);
}

#define GLOAD_LDS16(g, l) \
  __builtin_amdgcn_global_load_lds((const __attribute__((address_space(1))) unsigned*)(g), \
                                   (__attribute__((address_space(3))) unsigned*)(l), 16, 0, 0)

// ---------------- merged prep: zero deg + wprep + xprep (independent) ----------------

__global__ __launch_bounds__(256) void prep_kernel(const float* __restrict__ x,
    const float* __restrict__ W1, const float* __restrict__ W2, const float* __restrict__ W3,
    int* __restrict__ deg, ushort_t* __restrict__ xb,
    ushort_t* __restrict__ wt1, ushort_t* __restrict__ wt2, ushort_t* __restrict__ wt3,
    int N){
  const int gsz  = gridDim.x * 256;
  const int gtid = blockIdx.x * 256 + threadIdx.x;
  for (int i = gtid; i < N; i += gsz) deg[i] = 0;
  for (int i = gtid; i < 131072; i += gsz){
    const float* W; ushort_t* tp; int K, Nw, idx;
    if (i < 32768)      { W = W1; tp = wt1; K = 128; Nw = 256; idx = i; }
    else if (i < 98304) { W = W2; tp = wt2; K = 256; Nw = 256; idx = i - 32768; }
    else                { W = W3; tp = wt3; K = 256; Nw = 128; idx = i - 98304; }
    int k = idx / Nw, n = idx - k * Nw;
    tp[(size_t)n * K + k] = bf16_rne(W[idx]);
  }
  int totx = N * 16;   // N*128/8
  for (int i = gtid; i < totx; i += gsz){
    int base = i * 8;
    float4 a = *(const float4*)(x + base);
    float4 b = *(const float4*)(x + base + 4);
    short8 o;
    o[0] = (short)bf16_rne(a.x); o[1] = (short)bf16_rne(a.y);
    o[2] = (short)bf16_rne(a.z); o[3] = (short)bf16_rne(a.w);
    o[4] = (short)bf16_rne(b.x); o[5] = (short)bf16_rne(b.y);
    o[6] = (short)bf16_rne(b.z); o[7] = (short)bf16_rne(b.w);
    *(short8*)(xb + base) = o;
  }
}

// ---------------- CSR build ----------------

__global__ void deg_kernel(const int* __restrict__ edges, int* __restrict__ deg, int E){
  int i = blockIdx.x * 256 + threadIdx.x;
  if (i < E) atomicAdd(&deg[edges[2*i + 1]], 1);
}

__global__ __launch_bounds__(256) void scan_part_kernel(const int* __restrict__ deg,
                                                        int* __restrict__ partial, int n){
  int i = blockIdx.x * 256 + threadIdx.x;
  int v = (i < n) ? deg[i] : 0;
  #pragma unroll
  for (int o = 32; o > 0; o >>= 1) v += __shfl_xor(v, o);
  __shared__ int ws[4];
  if ((threadIdx.x & 63) == 0) ws[threadIdx.x >> 6] = v;
  __syncthreads();
  if (threadIdx.x == 0) partial[blockIdx.x] = ws[0] + ws[1] + ws[2] + ws[3];
}

__global__ __launch_bounds__(256) void scan_top_kernel(int* __restrict__ partial, int nb){
  int t = threadIdx.x;
  int lane = t & 63, w = t >> 6;
  int v = (t < nb) ? partial[t] : 0;
  int sc = v;
  #pragma unroll
  for (int o = 1; o < 64; o <<= 1){
    int x = __shfl_up(sc, o);
    if (lane >= o) sc += x;
  }
  __shared__ int wt[4];
  if (lane == 63) wt[w] = sc;
  __syncthreads();
  int base = 0;
  for (int j = 0; j < w; j++) base += wt[j];
  if (t < nb) partial[t] = base + sc - v;
}

__global__ __launch_bounds__(256) void scan_fin_kernel(const int* __restrict__ deg,
    const int* __restrict__ partial, int* __restrict__ row_ptr, int* __restrict__ cursor,
    float* __restrict__ inv, int n){
  int b = blockIdx.x, t = threadIdx.x;
  int i = b * 256 + t;
  int lane = t & 63, w = t >> 6;
  int v = (i < n) ? deg[i] : 0;
  int sc = v;
  #pragma unroll
  for (int o = 1; o < 64; o <<= 1){
    int x = __shfl_up(sc, o);
    if (lane >= o) sc += x;
  }
  __shared__ int wt[4];
  if (lane == 63) wt[w] = sc;
  __syncthreads();
  int base = partial[b];
  for (int j = 0; j < w; j++) base += wt[j];
  int excl = base + sc - v;
  if (i < n){
    row_ptr[i] = excl;
    cursor[i]  = excl;
    inv[i] = (v > 0) ? 1.0f / (float)v : 0.0f;
    if (i == n - 1) row_ptr[n] = excl + v;
  }
}

__global__ void scatter_kernel(const int* __restrict__ edges, int* __restrict__ cursor,
                               int* __restrict__ col, int E){
  int i = blockIdx.x * 256 + threadIdx.x;
  if (i < E){
    int s = edges[2*i], d = edges[2*i + 1];
    int p = atomicAdd(&cursor[d], 1);
    col[p] = s;
  }
}

// Deterministic col order per row (harness re-validates after replays).
__global__ __launch_bounds__(256) void sortrows_kernel(const int* __restrict__ row_ptr,
                                                       int* __restrict__ col, int n){
  int gw = (blockIdx.x * 256 + threadIdx.x) >> 6;
  int lane = threadIdx.x & 63;
  if (gw >= n) return;
  int s = row_ptr[gw], e = row_ptr[gw + 1];
  int len = e - s;
  if (len <= 1) return;
  if (len <= 64){
    int v = (lane < len) ? col[s + lane] : 0x7fffffff;
    #pragma unroll
    for (int k = 2; k <= 64; k <<= 1){
      #pragma unroll
      for (int j = k >> 1; j > 0; j >>= 1){
        int o = __shfl_xor(v, j);
        bool dirUp = ((lane & k) == 0);
        bool takeMin = (((lane & j) == 0) == dirUp);
        v = takeMin ? min(v, o) : max(v, o);
      }
    }
    if (lane < len) col[s + lane] = v;
  } else if (lane == 0){
    for (int i = s + 1; i < e; ++i){
      int v = col[i];
      int j = i - 1;
      while (j >= s && col[j] > v){ col[j + 1] = col[j]; --j; }
      col[j + 1] = v;
    }
  }
}

// ---------------- Fused layer-1: gather(xb) + GEMM W1 + leaky ----------------
// Per block (512 thr, 8 waves): 128 dst rows x all 256 cols, K=128.
// Phase A: 16 half-waves gather-sum xb rows (bit-identical tree to the old
//   spmm128b), bf16 -> LDS tA [16 gran][129 rows]x16B (pad 129: conflict-free).
// Phase B: standard BK=32 dbuf MFMA GEMM, B staged via global_load_lds.
// Epilogue = old MODE1 (leaky, bias masked by inv>0).

__global__ __launch_bounds__(512) void fgemm1_kernel(
    const ushort_t* __restrict__ xb, const int* __restrict__ row_ptr,
    const int* __restrict__ col, const float* __restrict__ invv,
    const ushort_t* __restrict__ Bt, const float* __restrict__ bias,
    ushort_t* __restrict__ out, int M){
  __shared__ ushort_t tA[16 * 129 * 8];   // 33 KB
  __shared__ ushort_t tB[2][8192];        // 2 x 16 KB
  const int tid = threadIdx.x;
  const int br  = blockIdx.x * 128;

  // ---- phase A: gather ----
  {
    int hw  = tid >> 5;         // 0..15
    int l32 = tid & 31;
    int off = l32 * 4;
    for (int p = 0; p < 8; ++p){
      int r = p * 16 + hw;
      int dst = br + r;
      float f0 = 0.f, f1 = 0.f, f2 = 0.f, f3 = 0.f;
      if (dst < M){
        int s = row_ptr[dst], e = row_ptr[dst + 1];
        float ir = invv[dst];
        float4 a0 = make_float4(0.f,0.f,0.f,0.f), a1 = make_float4(0.f,0.f,0.f,0.f);
        float4 a2 = make_float4(0.f,0.f,0.f,0.f), a3 = make_float4(0.f,0.f,0.f,0.f);
        int i = s;
        for (; i + 3 < e; i += 4){
          int c0 = col[i], c1 = col[i+1], c2 = col[i+2], c3 = col[i+3];
          ushort4 u0 = *(const ushort4*)(xb + (size_t)c0 * 128 + off);
          ushort4 u1 = *(const ushort4*)(xb + (size_t)c1 * 128 + off);
          ushort4 u2 = *(const ushort4*)(xb + (size_t)c2 * 128 + off);
          ushort4 u3 = *(const ushort4*)(xb + (size_t)c3 * 128 + off);
          a0.x += bf16_to_f(u0.x); a0.y += bf16_to_f(u0.y); a0.z += bf16_to_f(u0.z); a0.w += bf16_to_f(u0.w);
          a1.x += bf16_to_f(u1.x); a1.y += bf16_to_f(u1.y); a1.z += bf16_to_f(u1.z); a1.w += bf16_to_f(u1.w);
          a2.x += bf16_to_f(u2.x); a2.y += bf16_to_f(u2.y); a2.z += bf16_to_f(u2.z); a2.w += bf16_to_f(u2.w);
          a3.x += bf16_to_f(u3.x); a3.y += bf16_to_f(u3.y); a3.z += bf16_to_f(u3.z); a3.w += bf16_to_f(u3.w);
        }
        for (; i < e; ++i){
          int c0 = col[i];
          ushort4 u0 = *(const ushort4*)(xb + (size_t)c0 * 128 + off);
          a0.x += bf16_to_f(u0.x); a0.y += bf16_to_f(u0.y); a0.z += bf16_to_f(u0.z); a0.w += bf16_to_f(u0.w);
        }
        f0 = ((a0.x + a1.x) + (a2.x + a3.x)) * ir;
        f1 = ((a0.y + a1.y) + (a2.y + a3.y)) * ir;
        f2 = ((a0.z + a1.z) + (a2.z + a3.z)) * ir;
        f3 = ((a0.w + a1.w) + (a2.w + a3.w)) * ir;
      }
      ushort4 ov;
      ov.x = bf16_rne(f0); ov.y = bf16_rne(f1);
      ov.z = bf16_rne(f2); ov.w = bf16_rne(f3);
      int g = l32 >> 1, half = l32 & 1;
      *(ushort4*)(tA + ((g * 129 + r) * 8 + half * 4)) = ov;
    }
  }

  // ---- phase B: GEMM ----
  const int lane = tid & 63;
  const int wid  = tid >> 6;     // 0..7
  const int wrow = wid >> 2;     // 0..1
  const int wcol = wid & 3;      // 0..3
  const int lg   = lane >> 4;    // 0..3

  floatx4 acc[4][4];
  #pragma unroll
  for (int i = 0; i < 4; i++)
    #pragma unroll
    for (int j = 0; j < 4; j++) acc[i][j] = (floatx4){0.f, 0.f, 0.f, 0.f};

  auto STAGEB = [&](int b, int t){
    #pragma unroll
    for (int q = 0; q < 2; q++){
      int c = q * 512 + tid;          // 0..1023 chunks
      int g4 = c >> 8, cc = c & 255;
      GLOAD_LDS16(Bt + (size_t)cc * 128 + t * 32 + g4 * 8,
                  (char*)tB[b] + (size_t)c * 16);
    }
  };

  auto COMPUTEB = [&](int b, int t){
    const ushort_t* bufB = tB[b];
    short8 bh[4];
    #pragma unroll
    for (int nf = 0; nf < 4; nf++)
      bh[nf] = *(const short8*)(bufB + (lg * 256 + wcol * 64 + nf * 16 + (lane & 15)) * 8);
    #pragma unroll
    for (int mf = 0; mf < 4; mf++){
      int row = wrow * 64 + mf * 16 + (lane & 15);
      short8 ah = *(const short8*)(tA + ((t * 4 + lg) * 129 + row) * 8);
      #pragma unroll
      for (int nf = 0; nf < 4; nf++)
        acc[mf][nf] = __builtin_amdgcn_mfma_f32_16x16x32_bf16(ah, bh[nf], acc[mf][nf], 0, 0, 0);
    }
  };

  STAGEB(0, 0);
  __syncthreads();   // covers gather ds_writes + tB buf0
  #pragma unroll
  for (int t = 0; t < 4; ++t){
    if (t < 3) STAGEB((t + 1) & 1, t + 1);
    COMPUTEB(t & 1, t);
    __syncthreads();
  }

  // ---- epilogue (old MODE1, N=256) ----
  #pragma unroll
  for (int nf = 0; nf < 4; nf++){
    int c = wcol * 64 + nf * 16 + (lane & 15);
    float bv = bias[c];
    #pragma unroll
    for (int mf = 0; mf < 4; mf++){
      int rbase = br + wrow * 64 + mf * 16 + ((lane >> 4) << 2);
      #pragma unroll
      for (int j = 0; j < 4; j++){
        int r = rbase + j;
        if (r >= M) continue;
        float m = (invv[r] > 0.f) ? 1.f : 0.f;
        out[(size_t)r * 256 + c] = bf16_rne(leaky(acc[mf][nf][j] + m * bv));
      }
    }
  }
}

// ---------------- MFMA GEMM (plain bf16 x bf16), MODE 2 ----------------
// A: [M][K] bf16, Bt: [N][K] bf16. 128x128 tile, 4 waves 2x2, BK=32, dbuf.

__global__ __launch_bounds__(256) void gemm_mfma_kernel(
    const ushort_t* __restrict__ A, const ushort_t* __restrict__ Bt,
    const float* __restrict__ bias, ushort_t* __restrict__ Cp,
    int M, int K, int N){
  __shared__ ushort_t lds[2][8192];
  const int tid  = threadIdx.x;
  const int lane = tid & 63;
  const int wid  = tid >> 6;
  const int wrow = wid >> 1;
  const int wcol = wid & 1;
  const int br = blockIdx.x * 128;
  const int bc = blockIdx.y * 128;

  floatx4 acc[4][4];
  #pragma unroll
  for (int i = 0; i < 4; i++)
    #pragma unroll
    for (int j = 0; j < 4; j++) acc[i][j] = (floatx4){0.f, 0.f, 0.f, 0.f};

  auto STAGE = [&](int b, int k0){
    char* bufA = (char*)&lds[b][0];
    char* bufB = (char*)&lds[b][4096];
    #pragma unroll
    for (int q = 0; q < 2; q++){
      int c = q * 256 + tid;
      int g = c >> 7, r = c & 127;
      int grow = br + r;
      if (grow < M)
        GLOAD_LDS16(A + (size_t)grow * K + k0 + g * 8,
                    bufA + (q * 256 + wid * 64) * 16);
    }
    #pragma unroll
    for (int q = 0; q < 2; q++){
      int c = q * 256 + tid;
      int g = c >> 7, colc = c & 127;
      int gcol = bc + colc;
      GLOAD_LDS16(Bt + (size_t)gcol * K + k0 + g * 8,
                  bufB + (q * 256 + wid * 64) * 16);
    }
  };

  auto COMPUTE = [&](int b){
    const ushort_t* bufA = &lds[b][0];
    const ushort_t* bufB = &lds[b][4096];
    const int gsel = (lane >> 4) * 1024;
    short8 bh[4];
    #pragma unroll
    for (int nf = 0; nf < 4; nf++)
      bh[nf] = *(const short8*)(bufB + gsel + (wcol * 64 + nf * 16 + (lane & 15)) * 8);
    #pragma unroll
    for (int mf = 0; mf < 4; mf++){
      short8 ah = *(const short8*)(bufA + gsel + (wrow * 64 + mf * 16 + (lane & 15)) * 8);
      #pragma unroll
      for (int nf = 0; nf < 4; nf++)
        acc[mf][nf] = __builtin_amdgcn_mfma_f32_16x16x32_bf16(ah, bh[nf], acc[mf][nf], 0, 0, 0);
    }
  };

  const int nt = K >> 5;
  STAGE(0, 0);
  __syncthreads();
  for (int t = 0; t < nt; ++t){
    if (t + 1 < nt) STAGE((t + 1) & 1, (t + 1) << 5);
    COMPUTE(t & 1);
    __syncthreads();
  }

  const int r0 = br + wrow * 64;
  const int c0 = bc + wcol * 64;
  #pragma unroll
  for (int nf = 0; nf < 4; nf++){
    int col = c0 + nf * 16 + (lane & 15);
    float bv = bias[col];
    #pragma unroll
    for (int mf = 0; mf < 4; mf++){
      int rbase = r0 + mf * 16 + ((lane >> 4) << 2);
      #pragma unroll
      for (int j = 0; j < 4; j++){
        int r = rbase + j;
        if (r >= M) continue;
        Cp[(size_t)r * N + col] = bf16_rne(acc[mf][nf][j] + bv);
      }
    }
  }
}

// ---------------- SpMM kernels (CSR gather, bf16 src, f32 accum) ----------------

// s2 (bf16 [n][256]) -> h2 (bf16 [n][256]); h = leaky(inv * sum)
__global__ __launch_bounds__(256) void spmm256b_leaky_kernel(const ushort_t* __restrict__ sup,
    const int* __restrict__ row_ptr, const int* __restrict__ col,
    const float* __restrict__ inv, ushort_t* __restrict__ out, int n){
  int gw = (blockIdx.x * 256 + threadIdx.x) >> 6;
  int lane = threadIdx.x & 63;
  if (gw >= n) return;
  int s = row_ptr[gw], e = row_ptr[gw + 1];
  float ir = inv[gw];
  int off = lane * 4;
  float4 a0 = make_float4(0.f,0.f,0.f,0.f), a1 = make_float4(0.f,0.f,0.f,0.f);
  float4 a2 = make_float4(0.f,0.f,0.f,0.f), a3 = make_float4(0.f,0.f,0.f,0.f);
  int i = s;
  for (; i + 3 < e; i += 4){
    int c0 = col[i], c1 = col[i+1], c2 = col[i+2], c3 = col[i+3];
    ushort4 u0 = *(const ushort4*)(sup + (size_t)c0 * 256 + off);
    ushort4 u1 = *(const ushort4*)(sup + (size_t)c1 * 256 + off);
    ushort4 u2 = *(const ushort4*)(sup + (size_t)c2 * 256 + off);
    ushort4 u3 = *(const ushort4*)(sup + (size_t)c3 * 256 + off);
    a0.x += bf16_to_f(u0.x); a0.y += bf16_to_f(u0.y); a0.z += bf16_to_f(u0.z); a0.w += bf16_to_f(u0.w);
    a1.x += bf16_to_f(u1.x); a1.y += bf16_to_f(u1.y); a1.z += bf16_to_f(u1.z); a1.w += bf16_to_f(u1.w);
    a2.x += bf16_to_f(u2.x); a2.y += bf16_to_f(u2.y); a2.z += bf16_to_f(u2.z); a2.w += bf16_to_f(u2.w);
    a3.x += bf16_to_f(u3.x); a3.y += bf16_to_f(u3.y); a3.z += bf16_to_f(u3.z); a3.w += bf16_to_f(u3.w);
  }
  for (; i < e; ++i){
    int c0 = col[i];
    ushort4 u0 = *(const ushort4*)(sup + (size_t)c0 * 256 + off);
    a0.x += bf16_to_f(u0.x); a0.y += bf16_to_f(u0.y); a0.z += bf16_to_f(u0.z); a0.w += bf16_to_f(u0.w);
  }
  ushort4 ov;
  ov.x = bf16_rne(leaky(((a0.x + a1.x) + (a2.x + a3.x)) * ir));
  ov.y = bf16_rne(leaky(((a0.y + a1.y) + (a2.y + a3.y)) * ir));
  ov.z = bf16_rne(leaky(((a0.z + a1.z) + (a2.z + a3.z)) * ir));
  ov.w = bf16_rne(leaky(((a0.w + a1.w) + (a2.w + a3.w)) * ir));
  *(ushort4*)(out + (size_t)gw * 256 + off) = ov;
}

// s3 (bf16 [n][128]) -> out f32 [n][128]; inv-scale + L2 row-normalize
__global__ __launch_bounds__(256) void spmm_normb_kernel(const ushort_t* __restrict__ sup,
    const int* __restrict__ row_ptr, const int* __restrict__ col,
    const float* __restrict__ inv, float* __restrict__ out, int n){
  int gw = (blockIdx.x * 256 + threadIdx.x) >> 5;
  int lane = threadIdx.x & 31;
  if (gw >= n) return;
  int s = row_ptr[gw], e = row_ptr[gw + 1];
  float ir = inv[gw];
  int off = lane * 4;
  float4 a0 = make_float4(0.f,0.f,0.f,0.f), a1 = make_float4(0.f,0.f,0.f,0.f);
  float4 a2 = make_float4(0.f,0.f,0.f,0.f), a3 = make_float4(0.f,0.f,0.f,0.f);
  int i = s;
  for (; i + 3 < e; i += 4){
    int c0 = col[i], c1 = col[i+1], c2 = col[i+2], c3 = col[i+3];
    ushort4 u0 = *(const ushort4*)(sup + (size_t)c0 * 128 + off);
    ushort4 u1 = *(const ushort4*)(sup + (size_t)c1 * 128 + off);
    ushort4 u2 = *(const ushort4*)(sup + (size_t)c2 * 128 + off);
    ushort4 u3 = *(const ushort4*)(sup + (size_t)c3 * 128 + off);
    a0.x += bf16_to_f(u0.x); a0.y += bf16_to_f(u0.y); a0.z += bf16_to_f(u0.z); a0.w += bf16_to_f(u0.w);
    a1.x += bf16_to_f(u1.x); a1.y += bf16_to_f(u1.y); a1.z += bf16_to_f(u1.z); a1.w += bf16_to_f(u1.w);
    a2.x += bf16_to_f(u2.x); a2.y += bf16_to_f(u2.y); a2.z += bf16_to_f(u2.z); a2.w += bf16_to_f(u2.w);
    a3.x += bf16_to_f(u3.x); a3.y += bf16_to_f(u3.y); a3.z += bf16_to_f(u3.z); a3.w += bf16_to_f(u3.w);
  }
  for (; i < e; ++i){
    int c0 = col[i];
    ushort4 u0 = *(const ushort4*)(sup + (size_t)c0 * 128 + off);
    a0.x += bf16_to_f(u0.x); a0.y += bf16_to_f(u0.y); a0.z += bf16_to_f(u0.z); a0.w += bf16_to_f(u0.w);
  }
  float v0 = ((a0.x + a1.x) + (a2.x + a3.x)) * ir;
  float v1 = ((a0.y + a1.y) + (a2.y + a3.y)) * ir;
  float v2 = ((a0.z + a1.z) + (a2.z + a3.z)) * ir;
  float v3 = ((a0.w + a1.w) + (a2.w + a3.w)) * ir;
  float ss = v0*v0 + v1*v1 + v2*v2 + v3*v3;
  #pragma unroll
  for (int o = 16; o > 0; o >>= 1) ss += __shfl_xor(ss, o);
  float scale = 1.0f / fmaxf(sqrtf(ss), 1e-12f);
  float4 ov;
  ov.x = v0 * scale; ov.y = v1 * scale; ov.z = v2 * scale; ov.w = v3 * scale;
  *(float4*)(out + (size_t)gw * 128 + off) = ov;
}

// ---------------- launch ----------------

extern "C" void kernel_launch(void* const* d_in, const int* in_sizes, int n_in,
                              void* d_out, int out_size, void* d_ws, size_t ws_size,
                              hipStream_t stream){
  const float* x  = (const float*)d_in[0];
  const float* W1 = (const float*)d_in[1];
  const float* b1 = (const float*)d_in[2];
  const float* W2 = (const float*)d_in[3];
  const float* b2 = (const float*)d_in[4];
  const float* W3 = (const float*)d_in[5];
  const float* b3 = (const float*)d_in[6];
  const int* edges = (const int*)d_in[7];
  int N = in_sizes[0] / 128;
  int E = in_sizes[7] / 2;

  char* w = (char*)d_ws;
  size_t off = 0;
  auto alloc = [&](size_t bytes)->char*{
    char* p = w + off;
    off = (off + bytes + 255) & ~(size_t)255;
    return p;
  };
  int nPart = (N + 255) / 256;
  int*   deg     = (int*)  alloc((size_t)N * 4);
  float* inv     = (float*)alloc((size_t)N * 4);
  int*   row_ptr = (int*)  alloc(((size_t)N + 1) * 4);
  int*   cursor  = (int*)  alloc((size_t)N * 4);
  int*   colidx  = (int*)  alloc((size_t)E * 4);
  int*   partial = (int*)  alloc((size_t)nPart * 4);
  ushort_t* wt1 = (ushort_t*)alloc((size_t)128 * 256 * 2);
  ushort_t* wt2 = (ushort_t*)alloc((size_t)256 * 256 * 2);
  ushort_t* wt3 = (ushort_t*)alloc((size_t)256 * 128 * 2);
  char* slabA = alloc((size_t)N * 1024);   // 51.2 MB
  char* slabB = alloc((size_t)N * 1024);   // 51.2 MB

  ushort_t* xb     = (ushort_t*)slabA;                       // [N][128] bf16
  ushort_t* s2_buf = (ushort_t*)(slabA + (size_t)N * 512);   // [N][256] bf16
  ushort_t* h1_buf = (ushort_t*)slabB;                       // [N][256] bf16
  ushort_t* h2_buf = (ushort_t*)(slabB + (size_t)N * 512);   // [N][256] bf16
  ushort_t* s3_buf = (ushort_t*)(slabA + (size_t)N * 256);   // [N][128] bf16

  // prep (zero deg + wprep + xprep) + CSR chain
  prep_kernel<<<1024, 256, 0, stream>>>(x, W1, W2, W3, deg, xb, wt1, wt2, wt3, N);
  int gE = (E + 255) / 256;
  deg_kernel<<<gE, 256, 0, stream>>>(edges, deg, E);
  scan_part_kernel<<<nPart, 256, 0, stream>>>(deg, partial, N);
  scan_top_kernel<<<1, 256, 0, stream>>>(partial, nPart);
  scan_fin_kernel<<<nPart, 256, 0, stream>>>(deg, partial, row_ptr, cursor, inv, N);
  scatter_kernel<<<gE, 256, 0, stream>>>(edges, cursor, colidx, E);
  sortrows_kernel<<<(N * 64 + 255) / 256, 256, 0, stream>>>(row_ptr, colidx, N);

  int gm = (N + 127) / 128;
  dim3 g12(gm, 2);
  dim3 g3 (gm, 1);
  int gS64 = (N * 64 + 255) / 256;
  int gS32 = (N * 32 + 255) / 256;

  // layer 1 (fused): h1 = bf16(leaky((A_hat xb)@W1 + mask*b1))
  fgemm1_kernel<<<gm, 512, 0, stream>>>(xb, row_ptr, colidx, inv, wt1, b1, h1_buf, N);
  // layer 2: s2 = bf16(h1@W2 + b2) ; h2 = bf16(leaky(A_hat s2))
  gemm_mfma_kernel<<<g12, 256, 0, stream>>>(h1_buf, wt2, b2, s2_buf, N, 256, 256);
  spmm256b_leaky_kernel<<<gS64, 256, 0, stream>>>(s2_buf, row_ptr, colidx, inv, h2_buf, N);
  // layer 3: s3 = bf16(h2@W3 + b3) ; out = normalize(A_hat s3)
  gemm_mfma_kernel<<<g3, 256, 0, stream>>>(h2_buf, wt3, b3, s3_buf, N, 256, 128);
  spmm_normb_kernel<<<gS32, 256, 0, stream>>>(s3_buf, row_ptr, colidx, inv, (float*)d_out, N);
}

// Round 14
// 334.941 us; speedup vs baseline: 3.0278x; 1.0035x over previous
//
#include <hip/hip_runtime.h>

#define NEG_SLOPE 0.2f

typedef __attribute__((ext_vector_type(8))) short short8;
typedef __attribute__((ext_vector_type(4))) float floatx4;
typedef unsigned short ushort_t;

static __device__ __forceinline__ float leaky(float x){ return x > 0.f ? x : NEG_SLOPE * x; }

static __device__ __forceinline__ unsigned short bf16_rne(float x){
  unsigned u = __float_as_uint(x);
  unsigned r = (u + 0x7fffu + ((u >> 16) & 1u)) >> 16;
  return (unsigned short)r;
}
static __device__ __forceinline__ float bf16_to_f(unsigned short h){
  return __uint_as_float(((unsigned)h) << 16);
}

#define GLOAD_LDS16(g, l) \
  __builtin_amdgcn_global_load_lds((const __attribute__((address_space(1))) unsigned*)(g), \
                                   (__attribute__((address_space(3))) unsigned*)(l), 16, 0, 0)

// ---------------- merged prep: zero deg + wprep + xprep (independent) ----------------

__global__ __launch_bounds__(256) void prep_kernel(const float* __restrict__ x,
    const float* __restrict__ W1, const float* __restrict__ W2, const float* __restrict__ W3,
    int* __restrict__ deg, ushort_t* __restrict__ xb,
    ushort_t* __restrict__ wt1, ushort_t* __restrict__ wt2, ushort_t* __restrict__ wt3,
    int N){
  const int gsz  = gridDim.x * 256;
  const int gtid = blockIdx.x * 256 + threadIdx.x;
  for (int i = gtid; i < N; i += gsz) deg[i] = 0;
  for (int i = gtid; i < 131072; i += gsz){
    const float* W; ushort_t* tp; int K, Nw, idx;
    if (i < 32768)      { W = W1; tp = wt1; K = 128; Nw = 256; idx = i; }
    else if (i < 98304) { W = W2; tp = wt2; K = 256; Nw = 256; idx = i - 32768; }
    else                { W = W3; tp = wt3; K = 256; Nw = 128; idx = i - 98304; }
    int k = idx / Nw, n = idx - k * Nw;
    tp[(size_t)n * K + k] = bf16_rne(W[idx]);
  }
  int totx = N * 16;   // N*128/8
  for (int i = gtid; i < totx; i += gsz){
    int base = i * 8;
    float4 a = *(const float4*)(x + base);
    float4 b = *(const float4*)(x + base + 4);
    short8 o;
    o[0] = (short)bf16_rne(a.x); o[1] = (short)bf16_rne(a.y);
    o[2] = (short)bf16_rne(a.z); o[3] = (short)bf16_rne(a.w);
    o[4] = (short)bf16_rne(b.x); o[5] = (short)bf16_rne(b.y);
    o[6] = (short)bf16_rne(b.z); o[7] = (short)bf16_rne(b.w);
    *(short8*)(xb + base) = o;
  }
}

// ---------------- CSR build ----------------

__global__ void deg_kernel(const int* __restrict__ edges, int* __restrict__ deg, int E){
  int i = blockIdx.x * 256 + threadIdx.x;
  if (i < E) atomicAdd(&deg[edges[2*i + 1]], 1);
}

__global__ __launch_bounds__(256) void scan_part_kernel(const int* __restrict__ deg,
                                                        int* __restrict__ partial, int n){
  int i = blockIdx.x * 256 + threadIdx.x;
  int v = (i < n) ? deg[i] : 0;
  #pragma unroll
  for (int o = 32; o > 0; o >>= 1) v += __shfl_xor(v, o);
  __shared__ int ws[4];
  if ((threadIdx.x & 63) == 0) ws[threadIdx.x >> 6] = v;
  __syncthreads();
  if (threadIdx.x == 0) partial[blockIdx.x] = ws[0] + ws[1] + ws[2] + ws[3];
}

__global__ __launch_bounds__(256) void scan_top_kernel(int* __restrict__ partial, int nb){
  int t = threadIdx.x;
  int lane = t & 63, w = t >> 6;
  int v = (t < nb) ? partial[t] : 0;
  int sc = v;
  #pragma unroll
  for (int o = 1; o < 64; o <<= 1){
    int x = __shfl_up(sc, o);
    if (lane >= o) sc += x;
  }
  __shared__ int wt[4];
  if (lane == 63) wt[w] = sc;
  __syncthreads();
  int base = 0;
  for (int j = 0; j < w; j++) base += wt[j];
  if (t < nb) partial[t] = base + sc - v;
}

__global__ __launch_bounds__(256) void scan_fin_kernel(const int* __restrict__ deg,
    const int* __restrict__ partial, int* __restrict__ row_ptr, int* __restrict__ cursor,
    float* __restrict__ inv, int n){
  int b = blockIdx.x, t = threadIdx.x;
  int i = b * 256 + t;
  int lane = t & 63, w = t >> 6;
  int v = (i < n) ? deg[i] : 0;
  int sc = v;
  #pragma unroll
  for (int o = 1; o < 64; o <<= 1){
    int x = __shfl_up(sc, o);
    if (lane >= o) sc += x;
  }
  __shared__ int wt[4];
  if (lane == 63) wt[w] = sc;
  __syncthreads();
  int base = partial[b];
  for (int j = 0; j < w; j++) base += wt[j];
  int excl = base + sc - v;
  if (i < n){
    row_ptr[i] = excl;
    cursor[i]  = excl;
    inv[i] = (v > 0) ? 1.0f / (float)v : 0.0f;
    if (i == n - 1) row_ptr[n] = excl + v;
  }
}

__global__ void scatter_kernel(const int* __restrict__ edges, int* __restrict__ cursor,
                               int* __restrict__ col, int E){
  int i = blockIdx.x * 256 + threadIdx.x;
  if (i < E){
    int s = edges[2*i], d = edges[2*i + 1];
    int p = atomicAdd(&cursor[d], 1);
    col[p] = s;
  }
}

// Deterministic col order per row (harness re-validates after replays).
__global__ __launch_bounds__(256) void sortrows_kernel(const int* __restrict__ row_ptr,
                                                       int* __restrict__ col, int n){
  int gw = (blockIdx.x * 256 + threadIdx.x) >> 6;
  int lane = threadIdx.x & 63;
  if (gw >= n) return;
  int s = row_ptr[gw], e = row_ptr[gw + 1];
  int len = e - s;
  if (len <= 1) return;
  if (len <= 64){
    int v = (lane < len) ? col[s + lane] : 0x7fffffff;
    #pragma unroll
    for (int k = 2; k <= 64; k <<= 1){
      #pragma unroll
      for (int j = k >> 1; j > 0; j >>= 1){
        int o = __shfl_xor(v, j);
        bool dirUp = ((lane & k) == 0);
        bool takeMin = (((lane & j) == 0) == dirUp);
        v = takeMin ? min(v, o) : max(v, o);
      }
    }
    if (lane < len) col[s + lane] = v;
  } else if (lane == 0){
    for (int i = s + 1; i < e; ++i){
      int v = col[i];
      int j = i - 1;
      while (j >= s && col[j] > v){ col[j + 1] = col[j]; --j; }
      col[j + 1] = v;
    }
  }
}

// ---------------- MFMA GEMM (plain bf16 x bf16) ----------------
// A: [M][K] bf16, Bt: [N][K] bf16. f32 accum.
// 128x128 tile, 4 waves 2x2, BK=32, LDS double-buffered, one barrier/K-step.
// K-major granule-plane LDS (conflict-free). global_load_lds staging.
// MODE: 1 = bf16 out, leaky, bias masked by inv>0; 2 = bf16 out + bias.

template<int MODE>
__global__ __launch_bounds__(256) void gemm_mfma_kernel(
    const ushort_t* __restrict__ A, const ushort_t* __restrict__ Bt,
    const float* __restrict__ bias, const float* __restrict__ invv,
    ushort_t* __restrict__ Cp,
    int M, int K, int N){
  __shared__ ushort_t lds[2][8192];
  const int tid  = threadIdx.x;
  const int lane = tid & 63;
  const int wid  = tid >> 6;
  const int wrow = wid >> 1;
  const int wcol = wid & 1;
  const int br = blockIdx.x * 128;
  const int bc = blockIdx.y * 128;

  floatx4 acc[4][4];
  #pragma unroll
  for (int i = 0; i < 4; i++)
    #pragma unroll
    for (int j = 0; j < 4; j++) acc[i][j] = (floatx4){0.f, 0.f, 0.f, 0.f};

  auto STAGE = [&](int b, int k0){
    char* bufA = (char*)&lds[b][0];
    char* bufB = (char*)&lds[b][4096];
    #pragma unroll
    for (int q = 0; q < 2; q++){
      int c = q * 256 + tid;
      int g = c >> 7, r = c & 127;
      int grow = br + r;
      if (grow < M)
        GLOAD_LDS16(A + (size_t)grow * K + k0 + g * 8,
                    bufA + (q * 256 + wid * 64) * 16);
    }
    #pragma unroll
    for (int q = 0; q < 2; q++){
      int c = q * 256 + tid;
      int g = c >> 7, colc = c & 127;
      int gcol = bc + colc;
      GLOAD_LDS16(Bt + (size_t)gcol * K + k0 + g * 8,
                  bufB + (q * 256 + wid * 64) * 16);
    }
  };

  auto COMPUTE = [&](int b){
    const ushort_t* bufA = &lds[b][0];
    const ushort_t* bufB = &lds[b][4096];
    const int gsel = (lane >> 4) * 1024;
    short8 bh[4];
    #pragma unroll
    for (int nf = 0; nf < 4; nf++)
      bh[nf] = *(const short8*)(bufB + gsel + (wcol * 64 + nf * 16 + (lane & 15)) * 8);
    #pragma unroll
    for (int mf = 0; mf < 4; mf++){
      short8 ah = *(const short8*)(bufA + gsel + (wrow * 64 + mf * 16 + (lane & 15)) * 8);
      #pragma unroll
      for (int nf = 0; nf < 4; nf++)
        acc[mf][nf] = __builtin_amdgcn_mfma_f32_16x16x32_bf16(ah, bh[nf], acc[mf][nf], 0, 0, 0);
    }
  };

  const int nt = K >> 5;
  STAGE(0, 0);
  __syncthreads();
  for (int t = 0; t < nt; ++t){
    if (t + 1 < nt) STAGE((t + 1) & 1, (t + 1) << 5);
    COMPUTE(t & 1);
    __syncthreads();
  }

  const int r0 = br + wrow * 64;
  const int c0 = bc + wcol * 64;
  #pragma unroll
  for (int nf = 0; nf < 4; nf++){
    int col = c0 + nf * 16 + (lane & 15);
    float bv = bias[col];
    #pragma unroll
    for (int mf = 0; mf < 4; mf++){
      int rbase = r0 + mf * 16 + ((lane >> 4) << 2);
      #pragma unroll
      for (int j = 0; j < 4; j++){
        int r = rbase + j;
        if (r >= M) continue;
        if (MODE == 1){
          float m = (invv[r] > 0.f) ? 1.f : 0.f;
          Cp[(size_t)r * N + col] = bf16_rne(leaky(acc[mf][nf][j] + m * bv));
        } else {
          Cp[(size_t)r * N + col] = bf16_rne(acc[mf][nf][j] + bv);
        }
      }
    }
  }
}

// ---------------- SpMM kernels (CSR gather, bf16 src, f32 accum) ----------------

// xb (bf16 [n][128]) -> t (bf16 [n][128]); t = inv * sum
__global__ __launch_bounds__(256) void spmm128b_kernel(const ushort_t* __restrict__ xb,
    const int* __restrict__ row_ptr, const int* __restrict__ col,
    const float* __restrict__ inv, ushort_t* __restrict__ out, int n){
  int gw = (blockIdx.x * 256 + threadIdx.x) >> 5;
  int lane = threadIdx.x & 31;
  if (gw >= n) return;
  int s = row_ptr[gw], e = row_ptr[gw + 1];
  float ir = inv[gw];
  int off = lane * 4;
  float4 a0 = make_float4(0.f,0.f,0.f,0.f), a1 = make_float4(0.f,0.f,0.f,0.f);
  float4 a2 = make_float4(0.f,0.f,0.f,0.f), a3 = make_float4(0.f,0.f,0.f,0.f);
  int i = s;
  for (; i + 3 < e; i += 4){
    int c0 = col[i], c1 = col[i+1], c2 = col[i+2], c3 = col[i+3];
    ushort4 u0 = *(const ushort4*)(xb + (size_t)c0 * 128 + off);
    ushort4 u1 = *(const ushort4*)(xb + (size_t)c1 * 128 + off);
    ushort4 u2 = *(const ushort4*)(xb + (size_t)c2 * 128 + off);
    ushort4 u3 = *(const ushort4*)(xb + (size_t)c3 * 128 + off);
    a0.x += bf16_to_f(u0.x); a0.y += bf16_to_f(u0.y); a0.z += bf16_to_f(u0.z); a0.w += bf16_to_f(u0.w);
    a1.x += bf16_to_f(u1.x); a1.y += bf16_to_f(u1.y); a1.z += bf16_to_f(u1.z); a1.w += bf16_to_f(u1.w);
    a2.x += bf16_to_f(u2.x); a2.y += bf16_to_f(u2.y); a2.z += bf16_to_f(u2.z); a2.w += bf16_to_f(u2.w);
    a3.x += bf16_to_f(u3.x); a3.y += bf16_to_f(u3.y); a3.z += bf16_to_f(u3.z); a3.w += bf16_to_f(u3.w);
  }
  for (; i < e; ++i){
    int c0 = col[i];
    ushort4 u0 = *(const ushort4*)(xb + (size_t)c0 * 128 + off);
    a0.x += bf16_to_f(u0.x); a0.y += bf16_to_f(u0.y); a0.z += bf16_to_f(u0.z); a0.w += bf16_to_f(u0.w);
  }
  ushort4 ov;
  ov.x = bf16_rne(((a0.x + a1.x) + (a2.x + a3.x)) * ir);
  ov.y = bf16_rne(((a0.y + a1.y) + (a2.y + a3.y)) * ir);
  ov.z = bf16_rne(((a0.z + a1.z) + (a2.z + a3.z)) * ir);
  ov.w = bf16_rne(((a0.w + a1.w) + (a2.w + a3.w)) * ir);
  *(ushort4*)(out + (size_t)gw * 128 + off) = ov;
}

// s2 (bf16 [n][256]) -> h2 (bf16 [n][256]); h = leaky(inv * sum)
__global__ __launch_bounds__(256) void spmm256b_leaky_kernel(const ushort_t* __restrict__ sup,
    const int* __restrict__ row_ptr, const int* __restrict__ col,
    const float* __restrict__ inv, ushort_t* __restrict__ out, int n){
  int gw = (blockIdx.x * 256 + threadIdx.x) >> 6;
  int lane = threadIdx.x & 63;
  if (gw >= n) return;
  int s = row_ptr[gw], e = row_ptr[gw + 1];
  float ir = inv[gw];
  int off = lane * 4;
  float4 a0 = make_float4(0.f,0.f,0.f,0.f), a1 = make_float4(0.f,0.f,0.f,0.f);
  float4 a2 = make_float4(0.f,0.f,0.f,0.f), a3 = make_float4(0.f,0.f,0.f,0.f);
  int i = s;
  for (; i + 3 < e; i += 4){
    int c0 = col[i], c1 = col[i+1], c2 = col[i+2], c3 = col[i+3];
    ushort4 u0 = *(const ushort4*)(sup + (size_t)c0 * 256 + off);
    ushort4 u1 = *(const ushort4*)(sup + (size_t)c1 * 256 + off);
    ushort4 u2 = *(const ushort4*)(sup + (size_t)c2 * 256 + off);
    ushort4 u3 = *(const ushort4*)(sup + (size_t)c3 * 256 + off);
    a0.x += bf16_to_f(u0.x); a0.y += bf16_to_f(u0.y); a0.z += bf16_to_f(u0.z); a0.w += bf16_to_f(u0.w);
    a1.x += bf16_to_f(u1.x); a1.y += bf16_to_f(u1.y); a1.z += bf16_to_f(u1.z); a1.w += bf16_to_f(u1.w);
    a2.x += bf16_to_f(u2.x); a2.y += bf16_to_f(u2.y); a2.z += bf16_to_f(u2.z); a2.w += bf16_to_f(u2.w);
    a3.x += bf16_to_f(u3.x); a3.y += bf16_to_f(u3.y); a3.z += bf16_to_f(u3.z); a3.w += bf16_to_f(u3.w);
  }
  for (; i < e; ++i){
    int c0 = col[i];
    ushort4 u0 = *(const ushort4*)(sup + (size_t)c0 * 256 + off);
    a0.x += bf16_to_f(u0.x); a0.y += bf16_to_f(u0.y); a0.z += bf16_to_f(u0.z); a0.w += bf16_to_f(u0.w);
  }
  ushort4 ov;
  ov.x = bf16_rne(leaky(((a0.x + a1.x) + (a2.x + a3.x)) * ir));
  ov.y = bf16_rne(leaky(((a0.y + a1.y) + (a2.y + a3.y)) * ir));
  ov.z = bf16_rne(leaky(((a0.z + a1.z) + (a2.z + a3.z)) * ir));
  ov.w = bf16_rne(leaky(((a0.w + a1.w) + (a2.w + a3.w)) * ir));
  *(ushort4*)(out + (size_t)gw * 256 + off) = ov;
}

// s3 (bf16 [n][128]) -> out f32 [n][128]; inv-scale + L2 row-normalize
__global__ __launch_bounds__(256) void spmm_normb_kernel(const ushort_t* __restrict__ sup,
    const int* __restrict__ row_ptr, const int* __restrict__ col,
    const float* __restrict__ inv, float* __restrict__ out, int n){
  int gw = (blockIdx.x * 256 + threadIdx.x) >> 5;
  int lane = threadIdx.x & 31;
  if (gw >= n) return;
  int s = row_ptr[gw], e = row_ptr[gw + 1];
  float ir = inv[gw];
  int off = lane * 4;
  float4 a0 = make_float4(0.f,0.f,0.f,0.f), a1 = make_float4(0.f,0.f,0.f,0.f);
  float4 a2 = make_float4(0.f,0.f,0.f,0.f), a3 = make_float4(0.f,0.f,0.f,0.f);
  int i = s;
  for (; i + 3 < e; i += 4){
    int c0 = col[i], c1 = col[i+1], c2 = col[i+2], c3 = col[i+3];
    ushort4 u0 = *(const ushort4*)(sup + (size_t)c0 * 128 + off);
    ushort4 u1 = *(const ushort4*)(sup + (size_t)c1 * 128 + off);
    ushort4 u2 = *(const ushort4*)(sup + (size_t)c2 * 128 + off);
    ushort4 u3 = *(const ushort4*)(sup + (size_t)c3 * 128 + off);
    a0.x += bf16_to_f(u0.x); a0.y += bf16_to_f(u0.y); a0.z += bf16_to_f(u0.z); a0.w += bf16_to_f(u0.w);
    a1.x += bf16_to_f(u1.x); a1.y += bf16_to_f(u1.y); a1.z += bf16_to_f(u1.z); a1.w += bf16_to_f(u1.w);
    a2.x += bf16_to_f(u2.x); a2.y += bf16_to_f(u2.y); a2.z += bf16_to_f(u2.z); a2.w += bf16_to_f(u2.w);
    a3.x += bf16_to_f(u3.x); a3.y += bf16_to_f(u3.y); a3.z += bf16_to_f(u3.z); a3.w += bf16_to_f(u3.w);
  }
  for (; i < e; ++i){
    int c0 = col[i];
    ushort4 u0 = *(const ushort4*)(sup + (size_t)c0 * 128 + off);
    a0.x += bf16_to_f(u0.x); a0.y += bf16_to_f(u0.y); a0.z += bf16_to_f(u0.z); a0.w += bf16_to_f(u0.w);
  }
  float v0 = ((a0.x + a1.x) + (a2.x + a3.x)) * ir;
  float v1 = ((a0.y + a1.y) + (a2.y + a3.y)) * ir;
  float v2 = ((a0.z + a1.z) + (a2.z + a3.z)) * ir;
  float v3 = ((a0.w + a1.w) + (a2.w + a3.w)) * ir;
  float ss = v0*v0 + v1*v1 + v2*v2 + v3*v3;
  #pragma unroll
  for (int o = 16; o > 0; o >>= 1) ss += __shfl_xor(ss, o);
  float scale = 1.0f / fmaxf(sqrtf(ss), 1e-12f);
  float4 ov;
  ov.x = v0 * scale; ov.y = v1 * scale; ov.z = v2 * scale; ov.w = v3 * scale;
  *(float4*)(out + (size_t)gw * 128 + off) = ov;
}

// ---------------- launch ----------------

extern "C" void kernel_launch(void* const* d_in, const int* in_sizes, int n_in,
                              void* d_out, int out_size, void* d_ws, size_t ws_size,
                              hipStream_t stream){
  const float* x  = (const float*)d_in[0];
  const float* W1 = (const float*)d_in[1];
  const float* b1 = (const float*)d_in[2];
  const float* W2 = (const float*)d_in[3];
  const float* b2 = (const float*)d_in[4];
  const float* W3 = (const float*)d_in[5];
  const float* b3 = (const float*)d_in[6];
  const int* edges = (const int*)d_in[7];
  int N = in_sizes[0] / 128;
  int E = in_sizes[7] / 2;

  char* w = (char*)d_ws;
  size_t off = 0;
  auto alloc = [&](size_t bytes)->char*{
    char* p = w + off;
    off = (off + bytes + 255) & ~(size_t)255;
    return p;
  };
  int nPart = (N + 255) / 256;
  int*   deg     = (int*)  alloc((size_t)N * 4);
  float* inv     = (float*)alloc((size_t)N * 4);
  int*   row_ptr = (int*)  alloc(((size_t)N + 1) * 4);
  int*   cursor  = (int*)  alloc((size_t)N * 4);
  int*   colidx  = (int*)  alloc((size_t)E * 4);
  int*   partial = (int*)  alloc((size_t)nPart * 4);
  ushort_t* wt1 = (ushort_t*)alloc((size_t)128 * 256 * 2);
  ushort_t* wt2 = (ushort_t*)alloc((size_t)256 * 256 * 2);
  ushort_t* wt3 = (ushort_t*)alloc((size_t)256 * 128 * 2);
  char* slabA = alloc((size_t)N * 1024);   // 51.2 MB
  char* slabB = alloc((size_t)N * 1024);   // 51.2 MB

  ushort_t* xb     = (ushort_t*)slabA;                       // [N][128] bf16
  ushort_t* t_buf  = (ushort_t*)(slabA + (size_t)N * 256);   // [N][128] bf16
  ushort_t* s2_buf = (ushort_t*)(slabA + (size_t)N * 512);   // [N][256] bf16
  ushort_t* h1_buf = (ushort_t*)slabB;                       // [N][256] bf16
  ushort_t* h2_buf = (ushort_t*)(slabB + (size_t)N * 512);   // [N][256] bf16
  ushort_t* s3_buf = (ushort_t*)slabA;                       // [N][128] bf16 (aliases dead xb)

  // prep (zero deg + wprep + xprep) + CSR chain
  prep_kernel<<<1024, 256, 0, stream>>>(x, W1, W2, W3, deg, xb, wt1, wt2, wt3, N);
  int gE = (E + 255) / 256;
  deg_kernel<<<gE, 256, 0, stream>>>(edges, deg, E);
  scan_part_kernel<<<nPart, 256, 0, stream>>>(deg, partial, N);
  scan_top_kernel<<<1, 256, 0, stream>>>(partial, nPart);
  scan_fin_kernel<<<nPart, 256, 0, stream>>>(deg, partial, row_ptr, cursor, inv, N);
  scatter_kernel<<<gE, 256, 0, stream>>>(edges, cursor, colidx, E);
  sortrows_kernel<<<(N * 64 + 255) / 256, 256, 0, stream>>>(row_ptr, colidx, N);

  int gm = (N + 127) / 128;
  dim3 g12(gm, 2);
  dim3 g3 (gm, 1);
  int gS64 = (N * 64 + 255) / 256;
  int gS32 = (N * 32 + 255) / 256;

  // layer 1 (reordered): t = A_hat xb ; h1 = bf16(leaky(t@W1 + mask*b1))
  spmm128b_kernel<<<gS32, 256, 0, stream>>>(xb, row_ptr, colidx, inv, t_buf, N);
  gemm_mfma_kernel<1><<<g12, 256, 0, stream>>>(t_buf, wt1, b1, inv, h1_buf, N, 128, 256);
  // layer 2: s2 = bf16(h1@W2 + b2) ; h2 = bf16(leaky(A_hat s2))
  gemm_mfma_kernel<2><<<g12, 256, 0, stream>>>(h1_buf, wt2, b2, nullptr, s2_buf, N, 256, 256);
  spmm256b_leaky_kernel<<<gS64, 256, 0, stream>>>(s2_buf, row_ptr, colidx, inv, h2_buf, N);
  // layer 3: s3 = bf16(h2@W3 + b3) ; out = normalize(A_hat s3)
  gemm_mfma_kernel<2><<<g3, 256, 0, stream>>>(h2_buf, wt3, b3, nullptr, s3_buf, N, 256, 128);
  spmm_normb_kernel<<<gS32, 256, 0, stream>>>(s3_buf, row_ptr, colidx, inv, (float*)d_out, N);
}

// Round 15
// 276.909 us; speedup vs baseline: 3.6624x; 1.2096x over previous
//
#include <hip/hip_runtime.h>

#define NEG_SLOPE 0.2f

typedef __attribute__((ext_vector_type(8))) short short8;
typedef __attribute__((ext_vector_type(4))) float floatx4;
typedef unsigned short ushort_t;

#define BCAP 8192   // slots per bucket (mean fill 4096, >60 sigma headroom)

static __device__ __forceinline__ float leaky(float x){ return x > 0.f ? x : NEG_SLOPE * x; }

static __device__ __forceinline__ unsigned short bf16_rne(float x){
  unsigned u = __float_as_uint(x);
  unsigned r = (u + 0x7fffu + ((u >> 16) & 1u)) >> 16;
  return (unsigned short)r;
}
static __device__ __forceinline__ float bf16_to_f(unsigned short h){
  return __uint_as_float(((unsigned)h) << 16);
}

#define GLOAD_LDS16(g, l) \
  __builtin_amdgcn_global_load_lds((const __attribute__((address_space(1))) unsigned*)(g), \
                                   (__attribute__((address_space(3))) unsigned*)(l), 16, 0, 0)

// ---------------- merged prep: zero bucketCursor + wprep + xprep ----------------

__global__ __launch_bounds__(256) void prep_kernel(const float* __restrict__ x,
    const float* __restrict__ W1, const float* __restrict__ W2, const float* __restrict__ W3,
    int* __restrict__ bucketCursor, ushort_t* __restrict__ xb,
    ushort_t* __restrict__ wt1, ushort_t* __restrict__ wt2, ushort_t* __restrict__ wt3,
    int N, int B){
  const int gsz  = gridDim.x * 256;
  const int gtid = blockIdx.x * 256 + threadIdx.x;
  for (int i = gtid; i < B; i += gsz) bucketCursor[i] = 0;
  for (int i = gtid; i < 131072; i += gsz){
    const float* W; ushort_t* tp; int K, Nw, idx;
    if (i < 32768)      { W = W1; tp = wt1; K = 128; Nw = 256; idx = i; }
    else if (i < 98304) { W = W2; tp = wt2; K = 256; Nw = 256; idx = i - 32768; }
    else                { W = W3; tp = wt3; K = 256; Nw = 128; idx = i - 98304; }
    int k = idx / Nw, n = idx - k * Nw;
    tp[(size_t)n * K + k] = bf16_rne(W[idx]);
  }
  int totx = N * 16;   // N*128/8
  for (int i = gtid; i < totx; i += gsz){
    int base = i * 8;
    float4 a = *(const float4*)(x + base);
    float4 b = *(const float4*)(x + base + 4);
    short8 o;
    o[0] = (short)bf16_rne(a.x); o[1] = (short)bf16_rne(a.y);
    o[2] = (short)bf16_rne(a.z); o[3] = (short)bf16_rne(a.w);
    o[4] = (short)bf16_rne(b.x); o[5] = (short)bf16_rne(b.y);
    o[6] = (short)bf16_rne(b.z); o[7] = (short)bf16_rne(b.w);
    *(short8*)(xb + base) = o;
  }
}

// ---------------- bucket-staged CSR build ----------------
// K1: tile of 2048 edges/block -> dense (src,dst) runs in per-bucket regions.
// Bucket b = dst>>8 (B = ceil(N/256) <= 256). Claim contiguous run per
// (block,bucket) with ONE global atomic; writes are line-dense (no 16x HBM
// write amplification like the old random 4B scatter).

__global__ __launch_bounds__(256) void bucket_scatter_kernel(const int* __restrict__ edges,
    int* __restrict__ bucketCursor, uint2* __restrict__ pairs, int E){
  __shared__ int hist[256], base[256], cur[256];
  const int tid = threadIdx.x;
  const int t0  = blockIdx.x * 2048;
  hist[tid] = 0;
  __syncthreads();
  int myb[8], mys[8], myd[8];
  #pragma unroll
  for (int q = 0; q < 8; q++){
    int i = t0 + q * 256 + tid;
    int b = -1, s = 0, d = 0;
    if (i < E){
      s = edges[2*i]; d = edges[2*i + 1];
      b = d >> 8;
      atomicAdd(&hist[b], 1);
    }
    myb[q] = b; mys[q] = s; myd[q] = d;
  }
  __syncthreads();
  if (hist[tid] > 0) base[tid] = atomicAdd(&bucketCursor[tid], hist[tid]);
  cur[tid] = 0;
  __syncthreads();
  #pragma unroll
  for (int q = 0; q < 8; q++){
    int b = myb[q];
    if (b >= 0){
      int slot = base[b] + atomicAdd(&cur[b], 1);
      pairs[(size_t)b * BCAP + slot] = make_uint2((unsigned)mys[q], (unsigned)myd[q]);
    }
  }
}

// K2: one block per bucket. LDS histogram by dst&255 -> deg[] (all dsts of the
// bucket) and partial[b] = bucket count (replaces scan_part).
__global__ __launch_bounds__(256) void bucket_hist_kernel(const uint2* __restrict__ pairs,
    const int* __restrict__ bucketCursor, int* __restrict__ deg, int* __restrict__ partial,
    int N){
  __shared__ int hist[256];
  const int tid = threadIdx.x;
  const int b = blockIdx.x;
  const int cnt = bucketCursor[b];
  hist[tid] = 0;
  __syncthreads();
  for (int i = tid; i < cnt; i += 256){
    uint2 p = pairs[(size_t)b * BCAP + i];
    atomicAdd(&hist[p.y & 255], 1);
  }
  __syncthreads();
  int d = b * 256 + tid;
  if (d < N) deg[d] = hist[tid];
  if (tid == 0) partial[b] = cnt;
}

// K3: one block per bucket. Place col[row_ptr[dst] + cursor] = src.
// Bucket's col region (~16KB) is cache-hot + fully overwritten -> dense writeback.
// Within-row order nondeterministic; sortrows canonicalizes after.
__global__ __launch_bounds__(256) void bucket_place_kernel(const uint2* __restrict__ pairs,
    const int* __restrict__ bucketCursor, const int* __restrict__ row_ptr,
    int* __restrict__ col){
  __shared__ int cur[256];
  const int tid = threadIdx.x;
  const int b = blockIdx.x;
  const int cnt = bucketCursor[b];
  cur[tid] = 0;
  __syncthreads();
  for (int i = tid; i < cnt; i += 256){
    uint2 p = pairs[(size_t)b * BCAP + i];
    int d = (int)p.y;
    int pos = row_ptr[d] + atomicAdd(&cur[d & 255], 1);
    col[pos] = (int)p.x;
  }
}

// exclusive scan of partials (nb <= 256), single block
__global__ __launch_bounds__(256) void scan_top_kernel(int* __restrict__ partial, int nb){
  int t = threadIdx.x;
  int lane = t & 63, w = t >> 6;
  int v = (t < nb) ? partial[t] : 0;
  int sc = v;
  #pragma unroll
  for (int o = 1; o < 64; o <<= 1){
    int x = __shfl_up(sc, o);
    if (lane >= o) sc += x;
  }
  __shared__ int wt[4];
  if (lane == 63) wt[w] = sc;
  __syncthreads();
  int base = 0;
  for (int j = 0; j < w; j++) base += wt[j];
  if (t < nb) partial[t] = base + sc - v;
}

__global__ __launch_bounds__(256) void scan_fin_kernel(const int* __restrict__ deg,
    const int* __restrict__ partial, int* __restrict__ row_ptr,
    float* __restrict__ inv, int n){
  int b = blockIdx.x, t = threadIdx.x;
  int i = b * 256 + t;
  int lane = t & 63, w = t >> 6;
  int v = (i < n) ? deg[i] : 0;
  int sc = v;
  #pragma unroll
  for (int o = 1; o < 64; o <<= 1){
    int x = __shfl_up(sc, o);
    if (lane >= o) sc += x;
  }
  __shared__ int wt[4];
  if (lane == 63) wt[w] = sc;
  __syncthreads();
  int base = partial[b];
  for (int j = 0; j < w; j++) base += wt[j];
  int excl = base + sc - v;
  if (i < n){
    row_ptr[i] = excl;
    inv[i] = (v > 0) ? 1.0f / (float)v : 0.0f;
    if (i == n - 1) row_ptr[n] = excl + v;
  }
}

// Deterministic col order per row (harness re-validates after replays).
__global__ __launch_bounds__(256) void sortrows_kernel(const int* __restrict__ row_ptr,
                                                       int* __restrict__ col, int n){
  int gw = (blockIdx.x * 256 + threadIdx.x) >> 6;
  int lane = threadIdx.x & 63;
  if (gw >= n) return;
  int s = row_ptr[gw], e = row_ptr[gw + 1];
  int len = e - s;
  if (len <= 1) return;
  if (len <= 64){
    int v = (lane < len) ? col[s + lane] : 0x7fffffff;
    #pragma unroll
    for (int k = 2; k <= 64; k <<= 1){
      #pragma unroll
      for (int j = k >> 1; j > 0; j >>= 1){
        int o = __shfl_xor(v, j);
        bool dirUp = ((lane & k) == 0);
        bool takeMin = (((lane & j) == 0) == dirUp);
        v = takeMin ? min(v, o) : max(v, o);
      }
    }
    if (lane < len) col[s + lane] = v;
  } else if (lane == 0){
    for (int i = s + 1; i < e; ++i){
      int v = col[i];
      int j = i - 1;
      while (j >= s && col[j] > v){ col[j + 1] = col[j]; --j; }
      col[j + 1] = v;
    }
  }
}

// ---------------- MFMA GEMM (plain bf16 x bf16) ----------------
// A: [M][K] bf16, Bt: [N][K] bf16. f32 accum.
// 128x128 tile, 4 waves 2x2, BK=32, LDS double-buffered, one barrier/K-step.
// K-major granule-plane LDS (conflict-free). global_load_lds staging.
// MODE: 1 = bf16 out, leaky, bias masked by inv>0; 2 = bf16 out + bias.

template<int MODE>
__global__ __launch_bounds__(256) void gemm_mfma_kernel(
    const ushort_t* __restrict__ A, const ushort_t* __restrict__ Bt,
    const float* __restrict__ bias, const float* __restrict__ invv,
    ushort_t* __restrict__ Cp,
    int M, int K, int N){
  __shared__ ushort_t lds[2][8192];
  const int tid  = threadIdx.x;
  const int lane = tid & 63;
  const int wid  = tid >> 6;
  const int wrow = wid >> 1;
  const int wcol = wid & 1;
  const int br = blockIdx.x * 128;
  const int bc = blockIdx.y * 128;

  floatx4 acc[4][4];
  #pragma unroll
  for (int i = 0; i < 4; i++)
    #pragma unroll
    for (int j = 0; j < 4; j++) acc[i][j] = (floatx4){0.f, 0.f, 0.f, 0.f};

  auto STAGE = [&](int b, int k0){
    char* bufA = (char*)&lds[b][0];
    char* bufB = (char*)&lds[b][4096];
    #pragma unroll
    for (int q = 0; q < 2; q++){
      int c = q * 256 + tid;
      int g = c >> 7, r = c & 127;
      int grow = br + r;
      if (grow < M)
        GLOAD_LDS16(A + (size_t)grow * K + k0 + g * 8,
                    bufA + (q * 256 + wid * 64) * 16);
    }
    #pragma unroll
    for (int q = 0; q < 2; q++){
      int c = q * 256 + tid;
      int g = c >> 7, colc = c & 127;
      int gcol = bc + colc;
      GLOAD_LDS16(Bt + (size_t)gcol * K + k0 + g * 8,
                  bufB + (q * 256 + wid * 64) * 16);
    }
  };

  auto COMPUTE = [&](int b){
    const ushort_t* bufA = &lds[b][0];
    const ushort_t* bufB = &lds[b][4096];
    const int gsel = (lane >> 4) * 1024;
    short8 bh[4];
    #pragma unroll
    for (int nf = 0; nf < 4; nf++)
      bh[nf] = *(const short8*)(bufB + gsel + (wcol * 64 + nf * 16 + (lane & 15)) * 8);
    #pragma unroll
    for (int mf = 0; mf < 4; mf++){
      short8 ah = *(const short8*)(bufA + gsel + (wrow * 64 + mf * 16 + (lane & 15)) * 8);
      #pragma unroll
      for (int nf = 0; nf < 4; nf++)
        acc[mf][nf] = __builtin_amdgcn_mfma_f32_16x16x32_bf16(ah, bh[nf], acc[mf][nf], 0, 0, 0);
    }
  };

  const int nt = K >> 5;
  STAGE(0, 0);
  __syncthreads();
  for (int t = 0; t < nt; ++t){
    if (t + 1 < nt) STAGE((t + 1) & 1, (t + 1) << 5);
    COMPUTE(t & 1);
    __syncthreads();
  }

  const int r0 = br + wrow * 64;
  const int c0 = bc + wcol * 64;
  #pragma unroll
  for (int nf = 0; nf < 4; nf++){
    int col = c0 + nf * 16 + (lane & 15);
    float bv = bias[col];
    #pragma unroll
    for (int mf = 0; mf < 4; mf++){
      int rbase = r0 + mf * 16 + ((lane >> 4) << 2);
      #pragma unroll
      for (int j = 0; j < 4; j++){
        int r = rbase + j;
        if (r >= M) continue;
        if (MODE == 1){
          float m = (invv[r] > 0.f) ? 1.f : 0.f;
          Cp[(size_t)r * N + col] = bf16_rne(leaky(acc[mf][nf][j] + m * bv));
        } else {
          Cp[(size_t)r * N + col] = bf16_rne(acc[mf][nf][j] + bv);
        }
      }
    }
  }
}

// ---------------- SpMM kernels (CSR gather, bf16 src, f32 accum) ----------------

// xb (bf16 [n][128]) -> t (bf16 [n][128]); t = inv * sum
__global__ __launch_bounds__(256) void spmm128b_kernel(const ushort_t* __restrict__ xb,
    const int* __restrict__ row_ptr, const int* __restrict__ col,
    const float* __restrict__ inv, ushort_t* __restrict__ out, int n){
  int gw = (blockIdx.x * 256 + threadIdx.x) >> 5;
  int lane = threadIdx.x & 31;
  if (gw >= n) return;
  int s = row_ptr[gw], e = row_ptr[gw + 1];
  float ir = inv[gw];
  int off = lane * 4;
  float4 a0 = make_float4(0.f,0.f,0.f,0.f), a1 = make_float4(0.f,0.f,0.f,0.f);
  float4 a2 = make_float4(0.f,0.f,0.f,0.f), a3 = make_float4(0.f,0.f,0.f,0.f);
  int i = s;
  for (; i + 3 < e; i += 4){
    int c0 = col[i], c1 = col[i+1], c2 = col[i+2], c3 = col[i+3];
    ushort4 u0 = *(const ushort4*)(xb + (size_t)c0 * 128 + off);
    ushort4 u1 = *(const ushort4*)(xb + (size_t)c1 * 128 + off);
    ushort4 u2 = *(const ushort4*)(xb + (size_t)c2 * 128 + off);
    ushort4 u3 = *(const ushort4*)(xb + (size_t)c3 * 128 + off);
    a0.x += bf16_to_f(u0.x); a0.y += bf16_to_f(u0.y); a0.z += bf16_to_f(u0.z); a0.w += bf16_to_f(u0.w);
    a1.x += bf16_to_f(u1.x); a1.y += bf16_to_f(u1.y); a1.z += bf16_to_f(u1.z); a1.w += bf16_to_f(u1.w);
    a2.x += bf16_to_f(u2.x); a2.y += bf16_to_f(u2.y); a2.z += bf16_to_f(u2.z); a2.w += bf16_to_f(u2.w);
    a3.x += bf16_to_f(u3.x); a3.y += bf16_to_f(u3.y); a3.z += bf16_to_f(u3.z); a3.w += bf16_to_f(u3.w);
  }
  for (; i < e; ++i){
    int c0 = col[i];
    ushort4 u0 = *(const ushort4*)(xb + (size_t)c0 * 128 + off);
    a0.x += bf16_to_f(u0.x); a0.y += bf16_to_f(u0.y); a0.z += bf16_to_f(u0.z); a0.w += bf16_to_f(u0.w);
  }
  ushort4 ov;
  ov.x = bf16_rne(((a0.x + a1.x) + (a2.x + a3.x)) * ir);
  ov.y = bf16_rne(((a0.y + a1.y) + (a2.y + a3.y)) * ir);
  ov.z = bf16_rne(((a0.z + a1.z) + (a2.z + a3.z)) * ir);
  ov.w = bf16_rne(((a0.w + a1.w) + (a2.w + a3.w)) * ir);
  *(ushort4*)(out + (size_t)gw * 128 + off) = ov;
}

// s2 (bf16 [n][256]) -> h2 (bf16 [n][256]); h = leaky(inv * sum)
__global__ __launch_bounds__(256) void spmm256b_leaky_kernel(const ushort_t* __restrict__ sup,
    const int* __restrict__ row_ptr, const int* __restrict__ col,
    const float* __restrict__ inv, ushort_t* __restrict__ out, int n){
  int gw = (blockIdx.x * 256 + threadIdx.x) >> 6;
  int lane = threadIdx.x & 63;
  if (gw >= n) return;
  int s = row_ptr[gw], e = row_ptr[gw + 1];
  float ir = inv[gw];
  int off = lane * 4;
  float4 a0 = make_float4(0.f,0.f,0.f,0.f), a1 = make_float4(0.f,0.f,0.f,0.f);
  float4 a2 = make_float4(0.f,0.f,0.f,0.f), a3 = make_float4(0.f,0.f,0.f,0.f);
  int i = s;
  for (; i + 3 < e; i += 4){
    int c0 = col[i], c1 = col[i+1], c2 = col[i+2], c3 = col[i+3];
    ushort4 u0 = *(const ushort4*)(sup + (size_t)c0 * 256 + off);
    ushort4 u1 = *(const ushort4*)(sup + (size_t)c1 * 256 + off);
    ushort4 u2 = *(const ushort4*)(sup + (size_t)c2 * 256 + off);
    ushort4 u3 = *(const ushort4*)(sup + (size_t)c3 * 256 + off);
    a0.x += bf16_to_f(u0.x); a0.y += bf16_to_f(u0.y); a0.z += bf16_to_f(u0.z); a0.w += bf16_to_f(u0.w);
    a1.x += bf16_to_f(u1.x); a1.y += bf16_to_f(u1.y); a1.z += bf16_to_f(u1.z); a1.w += bf16_to_f(u1.w);
    a2.x += bf16_to_f(u2.x); a2.y += bf16_to_f(u2.y); a2.z += bf16_to_f(u2.z); a2.w += bf16_to_f(u2.w);
    a3.x += bf16_to_f(u3.x); a3.y += bf16_to_f(u3.y); a3.z += bf16_to_f(u3.z); a3.w += bf16_to_f(u3.w);
  }
  for (; i < e; ++i){
    int c0 = col[i];
    ushort4 u0 = *(const ushort4*)(sup + (size_t)c0 * 256 + off);
    a0.x += bf16_to_f(u0.x); a0.y += bf16_to_f(u0.y); a0.z += bf16_to_f(u0.z); a0.w += bf16_to_f(u0.w);
  }
  ushort4 ov;
  ov.x = bf16_rne(leaky(((a0.x + a1.x) + (a2.x + a3.x)) * ir));
  ov.y = bf16_rne(leaky(((a0.y + a1.y) + (a2.y + a3.y)) * ir));
  ov.z = bf16_rne(leaky(((a0.z + a1.z) + (a2.z + a3.z)) * ir));
  ov.w = bf16_rne(leaky(((a0.w + a1.w) + (a2.w + a3.w)) * ir));
  *(ushort4*)(out + (size_t)gw * 256 + off) = ov;
}

// s3 (bf16 [n][128]) -> out f32 [n][128]; inv-scale + L2 row-normalize
__global__ __launch_bounds__(256) void spmm_normb_kernel(const ushort_t* __restrict__ sup,
    const int* __restrict__ row_ptr, const int* __restrict__ col,
    const float* __restrict__ inv, float* __restrict__ out, int n){
  int gw = (blockIdx.x * 256 + threadIdx.x) >> 5;
  int lane = threadIdx.x & 31;
  if (gw >= n) return;
  int s = row_ptr[gw], e = row_ptr[gw + 1];
  float ir = inv[gw];
  int off = lane * 4;
  float4 a0 = make_float4(0.f,0.f,0.f,0.f), a1 = make_float4(0.f,0.f,0.f,0.f);
  float4 a2 = make_float4(0.f,0.f,0.f,0.f), a3 = make_float4(0.f,0.f,0.f,0.f);
  int i = s;
  for (; i + 3 < e; i += 4){
    int c0 = col[i], c1 = col[i+1], c2 = col[i+2], c3 = col[i+3];
    ushort4 u0 = *(const ushort4*)(sup + (size_t)c0 * 128 + off);
    ushort4 u1 = *(const ushort4*)(sup + (size_t)c1 * 128 + off);
    ushort4 u2 = *(const ushort4*)(sup + (size_t)c2 * 128 + off);
    ushort4 u3 = *(const ushort4*)(sup + (size_t)c3 * 128 + off);
    a0.x += bf16_to_f(u0.x); a0.y += bf16_to_f(u0.y); a0.z += bf16_to_f(u0.z); a0.w += bf16_to_f(u0.w);
    a1.x += bf16_to_f(u1.x); a1.y += bf16_to_f(u1.y); a1.z += bf16_to_f(u1.z); a1.w += bf16_to_f(u1.w);
    a2.x += bf16_to_f(u2.x); a2.y += bf16_to_f(u2.y); a2.z += bf16_to_f(u2.z); a2.w += bf16_to_f(u2.w);
    a3.x += bf16_to_f(u3.x); a3.y += bf16_to_f(u3.y); a3.z += bf16_to_f(u3.z); a3.w += bf16_to_f(u3.w);
  }
  for (; i < e; ++i){
    int c0 = col[i];
    ushort4 u0 = *(const ushort4*)(sup + (size_t)c0 * 128 + off);
    a0.x += bf16_to_f(u0.x); a0.y += bf16_to_f(u0.y); a0.z += bf16_to_f(u0.z); a0.w += bf16_to_f(u0.w);
  }
  float v0 = ((a0.x + a1.x) + (a2.x + a3.x)) * ir;
  float v1 = ((a0.y + a1.y) + (a2.y + a3.y)) * ir;
  float v2 = ((a0.z + a1.z) + (a2.z + a3.z)) * ir;
  float v3 = ((a0.w + a1.w) + (a2.w + a3.w)) * ir;
  float ss = v0*v0 + v1*v1 + v2*v2 + v3*v3;
  #pragma unroll
  for (int o = 16; o > 0; o >>= 1) ss += __shfl_xor(ss, o);
  float scale = 1.0f / fmaxf(sqrtf(ss), 1e-12f);
  float4 ov;
  ov.x = v0 * scale; ov.y = v1 * scale; ov.z = v2 * scale; ov.w = v3 * scale;
  *(float4*)(out + (size_t)gw * 128 + off) = ov;
}

// ---------------- launch ----------------

extern "C" void kernel_launch(void* const* d_in, const int* in_sizes, int n_in,
                              void* d_out, int out_size, void* d_ws, size_t ws_size,
                              hipStream_t stream){
  const float* x  = (const float*)d_in[0];
  const float* W1 = (const float*)d_in[1];
  const float* b1 = (const float*)d_in[2];
  const float* W2 = (const float*)d_in[3];
  const float* b2 = (const float*)d_in[4];
  const float* W3 = (const float*)d_in[5];
  const float* b3 = (const float*)d_in[6];
  const int* edges = (const int*)d_in[7];
  int N = in_sizes[0] / 128;
  int E = in_sizes[7] / 2;

  char* w = (char*)d_ws;
  size_t off = 0;
  auto alloc = [&](size_t bytes)->char*{
    char* p = w + off;
    off = (off + bytes + 255) & ~(size_t)255;
    return p;
  };
  int B = (N + 255) / 256;   // buckets (= scan partitions); N<=65536 here
  int*   deg     = (int*)  alloc((size_t)N * 4);
  float* inv     = (float*)alloc((size_t)N * 4);
  int*   row_ptr = (int*)  alloc(((size_t)N + 1) * 4);
  int*   colidx  = (int*)  alloc((size_t)E * 4);
  int*   partial = (int*)  alloc((size_t)B * 4);
  int*   bucketCursor = (int*)alloc((size_t)B * 4);
  ushort_t* wt1 = (ushort_t*)alloc((size_t)128 * 256 * 2);
  ushort_t* wt2 = (ushort_t*)alloc((size_t)256 * 256 * 2);
  ushort_t* wt3 = (ushort_t*)alloc((size_t)256 * 128 * 2);
  char* slabA = alloc((size_t)N * 1024);   // 51.2 MB
  char* slabB = alloc((size_t)N * 1024);   // 51.2 MB

  ushort_t* xb     = (ushort_t*)slabA;                       // [N][128] bf16
  ushort_t* t_buf  = (ushort_t*)(slabA + (size_t)N * 256);   // [N][128] bf16
  ushort_t* s2_buf = (ushort_t*)(slabA + (size_t)N * 512);   // [N][256] bf16
  ushort_t* h1_buf = (ushort_t*)slabB;                       // [N][256] bf16
  ushort_t* h2_buf = (ushort_t*)(slabB + (size_t)N * 512);   // [N][256] bf16
  ushort_t* s3_buf = (ushort_t*)slabA;                       // [N][128] bf16 (aliases dead xb)
  uint2*    pairs  = (uint2*)slabB;   // bucket staging (dead before gemm1 writes h1)

  // prep (zero cursors + wprep + xprep), then bucket-staged CSR build
  prep_kernel<<<1024, 256, 0, stream>>>(x, W1, W2, W3, bucketCursor, xb, wt1, wt2, wt3, N, B);
  int gT = (E + 2047) / 2048;
  bucket_scatter_kernel<<<gT, 256, 0, stream>>>(edges, bucketCursor, pairs, E);
  bucket_hist_kernel<<<B, 256, 0, stream>>>(pairs, bucketCursor, deg, partial, N);
  scan_top_kernel<<<1, 256, 0, stream>>>(partial, B);
  scan_fin_kernel<<<B, 256, 0, stream>>>(deg, partial, row_ptr, inv, N);
  bucket_place_kernel<<<B, 256, 0, stream>>>(pairs, bucketCursor, row_ptr, colidx);
  sortrows_kernel<<<(N * 64 + 255) / 256, 256, 0, stream>>>(row_ptr, colidx, N);

  int gm = (N + 127) / 128;
  dim3 g12(gm, 2);
  dim3 g3 (gm, 1);
  int gS64 = (N * 64 + 255) / 256;
  int gS32 = (N * 32 + 255) / 256;

  // layer 1 (reordered): t = A_hat xb ; h1 = bf16(leaky(t@W1 + mask*b1))
  spmm128b_kernel<<<gS32, 256, 0, stream>>>(xb, row_ptr, colidx, inv, t_buf, N);
  gemm_mfma_kernel<1><<<g12, 256, 0, stream>>>(t_buf, wt1, b1, inv, h1_buf, N, 128, 256);
  // layer 2: s2 = bf16(h1@W2 + b2) ; h2 = bf16(leaky(A_hat s2))
  gemm_mfma_kernel<2><<<g12, 256, 0, stream>>>(h1_buf, wt2, b2, nullptr, s2_buf, N, 256, 256);
  spmm256b_leaky_kernel<<<gS64, 256, 0, stream>>>(s2_buf, row_ptr, colidx, inv, h2_buf, N);
  // layer 3: s3 = bf16(h2@W3 + b3) ; out = normalize(A_hat s3)
  gemm_mfma_kernel<2><<<g3, 256, 0, stream>>>(h2_buf, wt3, b3, nullptr, s3_buf, N, 256, 128);
  spmm_normb_kernel<<<gS32, 256, 0, stream>>>(s3_buf, row_ptr, colidx, inv, (float*)d_out, N);
}